// Round 9
// baseline (422.251 us; speedup 1.0000x reference)
//
#include <hip/hip_runtime.h>
#include <hip/hip_bf16.h>

// Problem: B=64, N=320, C=768, H=12, D=64, num_t=64 (runtime-read), num_s=256.
// ESTABLISHED (R0-R7 evidence):
//   - all five input arrays are float32; OUTPUT BUFFER IS FLOAT32
//   - ws >= 126MB (4*per bf16 guard passed in R4-R7)
//   - d_in order == dict order; size-remap kept as insurance
// R9: m97-structure GEMMs -> K1 195->130us. R10/R11: attn FETCH 261->46MB.
// R12: attn 4 blocks/CU. R13/R14: K1 dbuf+counted vmcnt+T2: conflicts 8.8M->0,
//   dur flat ~120us => K1 at the 128^2 2-phase ceiling for this shape.
// R15/R16: T14 V-prefetch DEFEATED by compiler (VGPR 68->52 proves pv not kept
//   live); attn flat 126us. Counters: Occ 40 / VALU 27 / MFMA 5 / HBM 8% =>
//   latency-bound, needs TLP not ILP.
// R17 (this round): attn q-tile 32->16 rows => LDS 40960->20480B => 8 blocks/CU
//   (32 waves/CU, 2x TLP). Grid 7680->15360 (%8 ok). pv prefetch deleted.
//   __launch_bounds__(256,8) (VGPR<=64; was 52). K re-read cost ~+30MB at 8%
//   HBM - irrelevant. K1/K3/cvt byte-stable as comparators.

typedef __attribute__((ext_vector_type(8))) short short8;
typedef __attribute__((ext_vector_type(4))) float f32x4;
typedef __hip_bfloat16 bf16;

#define NTOK 320
#define CDIM 768
#define NHEAD 12
#define MFMA16(a,b,c) __builtin_amdgcn_mfma_f32_16x16x32_bf16((a),(b),(c),0,0,0)

__device__ __forceinline__ unsigned short bfbits(float v) {
    bf16 h = __float2bfloat16(v);
    unsigned short u; __builtin_memcpy(&u, &h, 2);
    return u;
}

// load 8 consecutive elements as a bf16 MFMA fragment
__device__ __forceinline__ short8 ldfrag(const bf16* p) { return *(const short8*)p; }
__device__ __forceinline__ short8 ldfrag(const float* p) {
    float4 a = *(const float4*)p;
    float4 b = *(const float4*)(p + 4);
    short8 r;
    r[0]=(short)bfbits(a.x); r[1]=(short)bfbits(a.y); r[2]=(short)bfbits(a.z); r[3]=(short)bfbits(a.w);
    r[4]=(short)bfbits(b.x); r[5]=(short)bfbits(b.y); r[6]=(short)bfbits(b.z); r[7]=(short)bfbits(b.w);
    return r;
}

// async global->LDS, 16B per lane. LDS dest must be wave-uniform base; HW adds lane*16.
__device__ __forceinline__ void stage16(const bf16* g, bf16* l) {
    __builtin_amdgcn_global_load_lds(
        (const __attribute__((address_space(1))) void*)g,
        (__attribute__((address_space(3))) void*)l, 16, 0, 0);
}

// fused f32 -> bf16 bulk convert over up to 3 segments, 8 elems/thread/iter
__global__ __launch_bounds__(256) void cvt3_kernel(const float* __restrict__ s0, bf16* __restrict__ d0, int n0,
                                                   const float* __restrict__ s1, bf16* __restrict__ d1, int n1,
                                                   const float* __restrict__ s2, bf16* __restrict__ d2, int n2)
{
    const int ntot = n0 + n1 + n2;
    int i = blockIdx.x * 256 + threadIdx.x;
    const int stride = gridDim.x * 256;
    for (; i < ntot; i += stride) {
        const float* s; bf16* d; int j = i;
        if (j < n0)              { s = s0; d = d0; }
        else if ((j -= n0) < n1) { s = s1; d = d1; }
        else                     { j -= n1; s = s2; d = d2; }
        const float4 a = ((const float4*)s)[2 * (size_t)j];
        const float4 b = ((const float4*)s)[2 * (size_t)j + 1];
        short8 r;
        r[0]=(short)bfbits(a.x); r[1]=(short)bfbits(a.y); r[2]=(short)bfbits(a.z); r[3]=(short)bfbits(a.w);
        r[4]=(short)bfbits(b.x); r[5]=(short)bfbits(b.y); r[6]=(short)bfbits(b.z); r[7]=(short)bfbits(b.w);
        ((short8*)d)[j] = r;
    }
}

// C = A @ Bm^T + bias. A: Mx768 row-major bf16. Bm: NOUTx768 row-major,
// bf16 if BF16B else f32 (converted on the fly).
// EPI=0: qkv scatter epilogue -> o0=Q,o1=K (B,H,N,D) bf16; o2=V^T (B,H,D,N) bf16.
// EPI=1: plain f32 store to o0 (ld=NOUT).
template<int NOUT, int EPI, int BF16B>
__global__ __launch_bounds__(256) void gemm_bt16(const bf16* __restrict__ A,
                                                 const void* __restrict__ Bmv,
                                                 const float* __restrict__ bias,
                                                 void* __restrict__ o0,
                                                 void* __restrict__ o1,
                                                 void* __restrict__ o2)
{
    __shared__ alignas(16) bf16 As[3 * 4096];   // 3 K-step buffers (24KB)
    __shared__ alignas(16) bf16 Bs[3 * 4096];   // 24KB -> 48KB total, 3 blk/CU
    const int tid  = threadIdx.x;
    const int lane = tid & 63;
    const int wv   = tid >> 6;
    const int r16  = lane & 15;
    const int kg   = lane >> 4;

    // bijective XCD swizzle: launched block F lands on XCD F%8; give each XCD a
    // contiguous chunk of tiles so A-strips and the B panel stay L2-local.
    constexpr int GX  = NOUT / 128;       // 18 (K1) or 6 (K3)
    constexpr int NWG = GX * 160;         // 2880 / 960, both % 8 == 0
    int flat = blockIdx.y * GX + blockIdx.x;
    flat = (flat & 7) * (NWG >> 3) + (flat >> 3);
    const int byy = flat / GX;
    const int bxx = flat - byy * GX;
    const int m0  = byy * 128;
    const int n0  = bxx * 128;
    const int wm  = (wv & 1) * 64;
    const int wn  = (wv >> 1) * 64;

    const bf16*  Ab   = A + (size_t)m0 * CDIM;
    const bf16*  Bb16 = (const bf16*)Bmv  + (size_t)n0 * CDIM;
    const float* Bb32 = (const float*)Bmv + (size_t)n0 * CDIM;

    const int ra0 = tid >> 2;           // staging row 0..63 (+64 for 2nd issue)

    f32x4 acc[4][4] = {};

    if constexpr (BF16B) {
        // T2 inverse source swizzle: LDS slot (row, chunk c) receives global
        // chunk c ^ ((row>>1)&3). Per-lane constant.
        const int ca_sw = (((tid & 3) ^ ((tid >> 3) & 3)) * 8);
        const bf16* gA0 = Ab   + (size_t)ra0 * CDIM + ca_sw;
        const bf16* gB0 = Bb16 + (size_t)ra0 * CDIM + ca_sw;
        // swizzled read chunk: kg ^ ((r16>>1)&3)  (row bases are mult. of 16)
        const int kgs = (kg ^ ((r16 >> 1) & 3)) * 8;

        auto stage = [&](int kt, int buf) {
            const int k0 = kt * 32;
            const size_t lb = (size_t)buf * 4096;
            stage16(gA0 + k0,             &As[lb + wv * 512]);
            stage16(gA0 + 64 * CDIM + k0, &As[lb + wv * 512 + 2048]);
            stage16(gB0 + k0,             &Bs[lb + wv * 512]);
            stage16(gB0 + 64 * CDIM + k0, &Bs[lb + wv * 512 + 2048]);
        };
        auto compute = [&](int buf) {
            const size_t lb = (size_t)buf * 4096;
            short8 af[4], bfr[4];
            #pragma unroll
            for (int mt = 0; mt < 4; mt++)
                af[mt] = *(const short8*)&As[lb + (wm + mt * 16 + r16) * 32 + kgs];
            #pragma unroll
            for (int nt = 0; nt < 4; nt++)
                bfr[nt] = *(const short8*)&Bs[lb + (wn + nt * 16 + r16) * 32 + kgs];
            __builtin_amdgcn_s_setprio(1);
            #pragma unroll
            for (int mt = 0; mt < 4; mt++)
                #pragma unroll
                for (int nt = 0; nt < 4; nt++)
                    acc[mt][nt] = MFMA16(af[mt], bfr[nt], acc[mt][nt]);
            __builtin_amdgcn_s_setprio(0);
        };

        // T4 pipeline: prefetch depth 2 over 3 buffers; counted vmcnt(4) keeps
        // the newest prefetch in flight across the barrier (never drain to 0
        // until the tail). Coverage: stage(t) issued at iter t-2, consumed at
        // iter t (~2 compute phases + 2 barriers ~ 500cyc).
        constexpr int NKT = CDIM / 32;   // 24
        stage(0, 0);
        stage(1, 1);
        for (int t = 0; t < NKT; ++t) {
            if (t < NKT - 1) { asm volatile("s_waitcnt vmcnt(4)" ::: "memory"); }
            else             { asm volatile("s_waitcnt vmcnt(0)" ::: "memory"); }
            __builtin_amdgcn_s_barrier();
            asm volatile("" ::: "memory");   // keep ds ops below the barrier
            if (t + 2 < NKT) stage(t + 2, (t + 2) % 3);
            compute(t % 3);
        }
    } else {
        // insurance path (ws too small for bf16 weights): original 2-barrier loop
        const int ca0 = (tid & 3) * 8;
        for (int k0 = 0; k0 < CDIM; k0 += 32) {
            short8 gb0 = ldfrag(Bb32 + (size_t)ra0        * CDIM + k0 + ca0);
            short8 gb1 = ldfrag(Bb32 + (size_t)(ra0 + 64) * CDIM + k0 + ca0);
            __syncthreads();
            stage16(Ab + (size_t)ra0        * CDIM + k0 + ca0, &As[(size_t)(wv * 64) * 8]);
            stage16(Ab + (size_t)(ra0 + 64) * CDIM + k0 + ca0, &As[(size_t)(wv * 64 + 256) * 8]);
            *(short8*)&Bs[(size_t)tid * 8]         = gb0;
            *(short8*)&Bs[(size_t)(tid + 256) * 8] = gb1;
            __syncthreads();

            short8 af[4], bfr[4];
            #pragma unroll
            for (int mt = 0; mt < 4; mt++)
                af[mt] = *(const short8*)&As[(wm + mt * 16 + r16) * 32 + kg * 8];
            #pragma unroll
            for (int nt = 0; nt < 4; nt++)
                bfr[nt] = *(const short8*)&Bs[(wn + nt * 16 + r16) * 32 + kg * 8];
            #pragma unroll
            for (int mt = 0; mt < 4; mt++)
                #pragma unroll
                for (int nt = 0; nt < 4; nt++)
                    acc[mt][nt] = MFMA16(af[mt], bfr[nt], acc[mt][nt]);
        }
    }

    // Epilogue. C/D layout (16x16x32): col = lane&15, row = (lane>>4)*4 + r
    #pragma unroll
    for (int nt = 0; nt < 4; nt++) {
        const int gn = n0 + wn + nt * 16 + r16;
        const float bv = bias[gn];
        if (EPI == 0) {
            const int which = gn / CDIM;
            const int rem   = gn - which * CDIM;
            const int hh    = rem >> 6;
            const int dd    = rem & 63;
            #pragma unroll
            for (int mt = 0; mt < 4; mt++) {
                const int gm0  = m0 + wm + mt * 16 + (lane >> 4) * 4;  // 4-aligned
                const int bidx = gm0 / NTOK;                   // 320 % 4 == 0
                const int nn0  = gm0 - bidx * NTOK;
                float v[4];
                #pragma unroll
                for (int r = 0; r < 4; r++) v[r] = acc[mt][nt][r] + bv;
                if (which == 0) {
                    bf16* q = (bf16*)o0 + ((size_t)(bidx * NHEAD + hh) * NTOK + nn0) * 64 + dd;
                    #pragma unroll
                    for (int r = 0; r < 4; r++) q[(size_t)r * 64] = __float2bfloat16(v[r]);
                } else if (which == 1) {
                    bf16* k = (bf16*)o1 + ((size_t)(bidx * NHEAD + hh) * NTOK + nn0) * 64 + dd;
                    #pragma unroll
                    for (int r = 0; r < 4; r++) k[(size_t)r * 64] = __float2bfloat16(v[r]);
                } else {
                    ushort4 p;
                    unsigned short* ps = (unsigned short*)&p;
                    #pragma unroll
                    for (int r = 0; r < 4; r++) ps[r] = bfbits(v[r]);
                    *(ushort4*)((bf16*)o2 + ((size_t)(bidx * NHEAD + hh) * 64 + dd) * NTOK + nn0) = p;
                }
            }
        } else {
            float* out = (float*)o0;
            #pragma unroll
            for (int mt = 0; mt < 4; mt++) {
                const int gm0 = m0 + wm + mt * 16 + (lane >> 4) * 4;
                #pragma unroll
                for (int r = 0; r < 4; r++)
                    out[(size_t)(gm0 + r) * NOUT + gn] = acc[mt][nt][r] + bv;
            }
        }
    }
}

// Attention. One block = (bh, qtile of 16 queries). 256 threads = 4 waves.
// S: 16 rows x 320 f32, XOR-swizzled within each 1280B row (f32 word w of row r
// lives at w ^ ((r&7)<<2); bf16 half h at h ^ ((r&7)<<3)). After phase 2 the
// row's first 640B hold packed bf16 P; 1/sum in the stale upper half (word
// 316^swz). LDS = 20480B exactly -> 8 blocks/CU (32 waves/CU).
#define ATTN_NWG (768 * 20)
__global__ __launch_bounds__(256, 8) void attn_kernel(const bf16* __restrict__ q_ws,
                                                      const bf16* __restrict__ k_ws,
                                                      const bf16* __restrict__ vt_ws,
                                                      bf16* __restrict__ attn,
                                                      const int* __restrict__ numt_p)
{
    __shared__ alignas(16) float S[16 * 320];

    const int tid  = threadIdx.x;
    const int lane = tid & 63;
    const int w    = tid >> 6;
    const int r16  = lane & 15;
    const int kg   = lane >> 4;

    // bijective XCD swizzle: 15360 % 8 == 0. All 20 q-tiles of a head (sharing
    // its 80KB K/V panel) land on the same XCD -> L2-local re-reads.
    int blk = blockIdx.x;
    blk = (blk & 7) * (ATTN_NWG / 8) + (blk >> 3);
    const int bh  = blk / 20;
    const int qt  = blk - bh * 20;
    const int b   = bh / NHEAD;
    const int h   = bh - b * NHEAD;
    const int q0  = qt * 16;

    const bf16* qp = q_ws  + (size_t)bh * NTOK * 64;
    const bf16* kp = k_ws  + (size_t)bh * NTOK * 64;
    const bf16* vp = vt_ws + (size_t)bh * 64 * NTOK;

    // issue Q fragment loads before the numt_p scalar read
    short8 qf[2];
    #pragma unroll
    for (int ks = 0; ks < 2; ks++)
        qf[ks] = ldfrag(qp + (size_t)(q0 + r16) * 64 + ks * 32 + kg * 8);

    int num_t = 64;
    if (numt_p) {
        int v = *numt_p;
        float f = __int_as_float(v);
        if (v >= 1 && v <= 319) num_t = v;
        else if (f >= 1.f && f <= 319.f) num_t = (int)f;
    }
    if (num_t <= 0 || num_t > NTOK || (num_t & 31)) num_t = 64;
    const int nk  = (q0 + 16 <= num_t) ? num_t : NTOK;
    const int nk16 = nk >> 4;

    // ---- Phase 1: S = (Q K^T) * scale ----
    const float scale = 0.125f;   // 1/sqrt(64)
    auto p1body = [&](int nt) {
        f32x4 a0 = {};
        #pragma unroll
        for (int ks = 0; ks < 2; ks++) {
            short8 kf = ldfrag(kp + (size_t)(nt * 16 + r16) * 64 + ks * 32 + kg * 8);
            a0 = MFMA16(qf[ks], kf, a0);
        }
        const int col = nt * 16 + r16;
        #pragma unroll
        for (int r = 0; r < 4; r++) {
            const int ro  = kg * 4 + r;          // 0..15
            const int swz = (ro & 7) << 2;
            S[ro * 320 + (col ^ swz)] = a0[r] * scale;
        }
    };
    if (nk16 == 20) {
        #pragma unroll
        for (int it = 0; it < 5; it++) p1body(w + it * 4);
    } else {
        for (int nt = w; nt < nk16; nt += 4) p1body(nt);
    }
    __syncthreads();

    // ---- Phase 2: row softmax. 16 threads per row (row = tid>>4, sub = tid&15,
    // a row's threads are 16 contiguous lanes of ONE wave). Reads S (f32),
    // writes P (bf16) overlaid on the same row bytes through the row swizzle.
    // Hazard-free: swizzle permutes within 128B groups; iteration k's read
    // group (bytes 256k..256k+255) never collides with writes j<k (those end
    // at byte 128(k+1) <= 256k), and within an iteration the read precedes the
    // dependent write. 1/sum stored post-reduction into stale word 316^swz.
    {
        const int row = tid >> 4;          // 0..15
        const int sub = tid & 15;
        const int swzw = (row & 7) << 2;   // f32-word swizzle
        const int swzh = (row & 7) << 3;   // bf16-half swizzle
        float* Sr = S + row * 320;
        bf16*  Pr = (bf16*)Sr;
        float mx = -1e30f;
        for (int c = sub * 4; c < nk; c += 64) {
            float4 t = *(float4*)&Sr[c ^ swzw];
            mx = fmaxf(mx, fmaxf(fmaxf(t.x, t.y), fmaxf(t.z, t.w)));
        }
        #pragma unroll
        for (int m = 1; m < 16; m <<= 1) mx = fmaxf(mx, __shfl_xor(mx, m));
        float sum = 0.f;
        for (int c = sub * 4; c < nk; c += 64) {
            float4 t = *(float4*)&Sr[c ^ swzw];
            t.x = __expf(t.x - mx); t.y = __expf(t.y - mx);
            t.z = __expf(t.z - mx); t.w = __expf(t.w - mx);
            sum += t.x + t.y + t.z + t.w;
            ushort4 p;
            p.x = bfbits(t.x); p.y = bfbits(t.y); p.z = bfbits(t.z); p.w = bfbits(t.w);
            *(ushort4*)&Pr[c ^ swzh] = p;     // 8B-aligned (swzh has no bits 0..2)
        }
        #pragma unroll
        for (int m = 1; m < 16; m <<= 1) sum += __shfl_xor(sum, m);
        if (sub == 0) Sr[316 ^ swzw] = 1.0f / sum;   // stale region, words>=160
    }
    __syncthreads();

    // ---- Phase 3: O = P @ V. A = packed bf16 P rows (lane reads row r16) via
    // ds_read_b128 through the swizzle; B = V^T rows (wave w owns output cols
    // w*16..w*16+15) from global. Hot path nk==320 fully unrolled.
    const bf16* Pbr = (const bf16*)(S + r16 * 320);
    const int pswzh = (r16 & 7) << 3;
    f32x4 o = {};
    auto p3body = [&](int ks) {
        short8 af = *(const short8*)&Pbr[(ks * 32 + kg * 8) ^ pswzh];
        short8 vf = ldfrag(vp + (size_t)(w * 16 + r16) * NTOK + ks * 32 + kg * 8);
        o = MFMA16(af, vf, o);
    };
    if (nk == NTOK) {
        #pragma unroll
        for (int ks = 0; ks < 10; ks++) p3body(ks);
    } else {
        for (int ks = 0; ks < (nk >> 5); ks++) p3body(ks);
    }
    {
        const int dd = w * 16 + r16;
        #pragma unroll
        for (int r = 0; r < 4; r++) {
            const int qrow  = kg * 4 + r;
            const float invs = S[qrow * 320 + (316 ^ ((qrow & 7) << 2))];
            const float val = o[r] * invs;
            const int token = q0 + qrow;
            attn[(((size_t)b * NTOK + token) * NHEAD + h) * 64 + dd] = __float2bfloat16(val);
        }
    }
}

extern "C" void kernel_launch(void* const* d_in, const int* in_sizes, int n_in,
                              void* d_out, int out_size, void* d_ws, size_t ws_size,
                              hipStream_t stream)
{
    float* out = (float*)d_out;

    // remap inputs by size (verified == dict order; kept as insurance)
    const float *x = nullptr, *w_qkv = nullptr, *b_qkv = nullptr,
                *w_proj = nullptr, *b_proj = nullptr;
    const int* numt_p = nullptr;
    for (int i = 0; i < n_in; i++) {
        switch (in_sizes[i]) {
            case 15728640: x      = (const float*)d_in[i]; break;  // (64,320,768)
            case 1769472:  w_qkv  = (const float*)d_in[i]; break;  // (2304,768)
            case 2304:     b_qkv  = (const float*)d_in[i]; break;  // (2304,)
            case 589824:   w_proj = (const float*)d_in[i]; break;  // (768,768)
            case 768:      b_proj = (const float*)d_in[i]; break;  // (768,)
            case 1:        if (!numt_p) numt_p = (const int*)d_in[i]; break;
            default: break;
        }
    }
    if (!x || !w_qkv || !b_qkv || !w_proj || !b_proj) return;

    const size_t per      = (size_t)64 * NHEAD * NTOK * 64;  // 15,728,640 elems
    const size_t wq_elems = (size_t)2304 * 768;              // 1,769,472
    const size_t wp_elems = (size_t)768 * 768;               //   589,824
    const size_t base_need = 4 * per * sizeof(bf16);               // 125,829,120 (proven ok)
    const size_t full_need = base_need + (wq_elems + wp_elems) * sizeof(bf16); // +4.7MB
    if (ws_size < base_need) return;
    const bool full = ws_size >= full_need;

    bf16* q_ws  = (bf16*)d_ws;
    bf16* k_ws  = q_ws  + per;
    bf16* vt_ws = k_ws  + per;
    bf16* attn  = vt_ws + per;   // doubles as x_bf16 (dead once K2 writes attn)
    bf16* x16   = attn;          // exact fit: per elems
    bf16* wq16  = attn + per;    // only touched when `full`
    bf16* wp16  = wq16 + wq_elems;

    // K0: fused f32->bf16 conversions (one launch)
    if (full)
        cvt3_kernel<<<2048, 256, 0, stream>>>(x, x16, (int)(per / 8),
                                              w_qkv, wq16, (int)(wq_elems / 8),
                                              w_proj, wp16, (int)(wp_elems / 8));
    else
        cvt3_kernel<<<2048, 256, 0, stream>>>(x, x16, (int)(per / 8),
                                              x, x16, 0, x, x16, 0);

    // K1: qkv = x @ w_qkv^T + b_qkv, scattered to Q,K,(V^T)
    if (full)
        gemm_bt16<2304, 0, 1><<<dim3(18, 160), 256, 0, stream>>>(
            x16, wq16, b_qkv, q_ws, k_ws, vt_ws);
    else
        gemm_bt16<2304, 0, 0><<<dim3(18, 160), 256, 0, stream>>>(
            x16, w_qkv, b_qkv, q_ws, k_ws, vt_ws);

    // K2: attention
    attn_kernel<<<ATTN_NWG, 256, 0, stream>>>(q_ws, k_ws, vt_ws, attn, numt_p);

    // K3: out = attn @ w_proj^T + b_proj (f32 stores)
    if (full)
        gemm_bt16<768, 1, 1><<<dim3(6, 160), 256, 0, stream>>>(
            attn, wp16, b_proj, out, nullptr, nullptr);
    else
        gemm_bt16<768, 1, 0><<<dim3(6, 160), 256, 0, stream>>>(
            attn, w_proj, b_proj, out, nullptr, nullptr);
}

// Round 10
// 387.341 us; speedup vs baseline: 1.0901x; 1.0901x over previous
//
#include <hip/hip_runtime.h>
#include <hip/hip_bf16.h>

// Problem: B=64, N=320, C=768, H=12, D=64, num_t=64 (runtime-read), num_s=256.
// ESTABLISHED (R0-R7 evidence):
//   - all five input arrays are float32; OUTPUT BUFFER IS FLOAT32
//   - ws >= 126MB (4*per bf16 guard passed in R4-R7)
//   - d_in order == dict order; size-remap kept as insurance
// LEDGER: R9 GEMM rebuild 195->~130. R10/R11 attn XCD swizzle FETCH 261->46MB
//   (time ~flat => attn NOT memory-bound). R12 attn 4blk/CU + unroll -> ~121
//   (best attn). R13/R14 K1 pipeline 130->119 BUT totals 389/390 vs R12-sub's
//   382 => shared template regressed K3 (small 960-block grid dislikes 48KB
//   3-buf). R15/R16 V-prefetch defeated by compiler (null). R17 16-row tiles:
//   Occ 40->82% yet 126->145us => attn is in-CU-serial bound; f32-S LDS
//   footprint makes queries/CU tiling-invariant. R12 attn is its local floor.
// R18 (this round): CONSOLIDATE at per-component best:
//   - attn: exact R12 kernel (proven 118-126us)
//   - K1:  R14 3-buffer counted-vmcnt template (proven 119-122us, 0 conflicts)
//   - K3:  Round-4 simple 2-barrier template (part of the 382us best total)
//   Two GEMM templates co-compiled (rule #19 noted; deltas still directional).

typedef __attribute__((ext_vector_type(8))) short short8;
typedef __attribute__((ext_vector_type(4))) float f32x4;
typedef __hip_bfloat16 bf16;

#define NTOK 320
#define CDIM 768
#define NHEAD 12
#define MFMA16(a,b,c) __builtin_amdgcn_mfma_f32_16x16x32_bf16((a),(b),(c),0,0,0)

__device__ __forceinline__ unsigned short bfbits(float v) {
    bf16 h = __float2bfloat16(v);
    unsigned short u; __builtin_memcpy(&u, &h, 2);
    return u;
}

// load 8 consecutive elements as a bf16 MFMA fragment
__device__ __forceinline__ short8 ldfrag(const bf16* p) { return *(const short8*)p; }
__device__ __forceinline__ short8 ldfrag(const float* p) {
    float4 a = *(const float4*)p;
    float4 b = *(const float4*)(p + 4);
    short8 r;
    r[0]=(short)bfbits(a.x); r[1]=(short)bfbits(a.y); r[2]=(short)bfbits(a.z); r[3]=(short)bfbits(a.w);
    r[4]=(short)bfbits(b.x); r[5]=(short)bfbits(b.y); r[6]=(short)bfbits(b.z); r[7]=(short)bfbits(b.w);
    return r;
}

// async global->LDS, 16B per lane. LDS dest must be wave-uniform base; HW adds lane*16.
__device__ __forceinline__ void stage16(const bf16* g, bf16* l) {
    __builtin_amdgcn_global_load_lds(
        (const __attribute__((address_space(1))) void*)g,
        (__attribute__((address_space(3))) void*)l, 16, 0, 0);
}

// fused f32 -> bf16 bulk convert over up to 3 segments, 8 elems/thread/iter
__global__ __launch_bounds__(256) void cvt3_kernel(const float* __restrict__ s0, bf16* __restrict__ d0, int n0,
                                                   const float* __restrict__ s1, bf16* __restrict__ d1, int n1,
                                                   const float* __restrict__ s2, bf16* __restrict__ d2, int n2)
{
    const int ntot = n0 + n1 + n2;
    int i = blockIdx.x * 256 + threadIdx.x;
    const int stride = gridDim.x * 256;
    for (; i < ntot; i += stride) {
        const float* s; bf16* d; int j = i;
        if (j < n0)              { s = s0; d = d0; }
        else if ((j -= n0) < n1) { s = s1; d = d1; }
        else                     { j -= n1; s = s2; d = d2; }
        const float4 a = ((const float4*)s)[2 * (size_t)j];
        const float4 b = ((const float4*)s)[2 * (size_t)j + 1];
        short8 r;
        r[0]=(short)bfbits(a.x); r[1]=(short)bfbits(a.y); r[2]=(short)bfbits(a.z); r[3]=(short)bfbits(a.w);
        r[4]=(short)bfbits(b.x); r[5]=(short)bfbits(b.y); r[6]=(short)bfbits(b.z); r[7]=(short)bfbits(b.w);
        ((short8*)d)[j] = r;
    }
}

// ---------- shared epilogue for both GEMM templates ----------
template<int NOUT, int EPI>
__device__ __forceinline__ void gemm_epilogue(f32x4 (&acc)[4][4],
                                              const float* __restrict__ bias,
                                              void* o0, void* o1, void* o2,
                                              int m0, int n0, int wm, int wn,
                                              int r16, int kg)
{
    #pragma unroll
    for (int nt = 0; nt < 4; nt++) {
        const int gn = n0 + wn + nt * 16 + r16;
        const float bv = bias[gn];
        if (EPI == 0) {
            const int which = gn / CDIM;
            const int rem   = gn - which * CDIM;
            const int hh    = rem >> 6;
            const int dd    = rem & 63;
            #pragma unroll
            for (int mt = 0; mt < 4; mt++) {
                const int gm0  = m0 + wm + mt * 16 + kg * 4;   // 4-aligned
                const int bidx = gm0 / NTOK;                   // 320 % 4 == 0
                const int nn0  = gm0 - bidx * NTOK;
                float v[4];
                #pragma unroll
                for (int r = 0; r < 4; r++) v[r] = acc[mt][nt][r] + bv;
                if (which == 0) {
                    bf16* q = (bf16*)o0 + ((size_t)(bidx * NHEAD + hh) * NTOK + nn0) * 64 + dd;
                    #pragma unroll
                    for (int r = 0; r < 4; r++) q[(size_t)r * 64] = __float2bfloat16(v[r]);
                } else if (which == 1) {
                    bf16* k = (bf16*)o1 + ((size_t)(bidx * NHEAD + hh) * NTOK + nn0) * 64 + dd;
                    #pragma unroll
                    for (int r = 0; r < 4; r++) k[(size_t)r * 64] = __float2bfloat16(v[r]);
                } else {
                    ushort4 p;
                    unsigned short* ps = (unsigned short*)&p;
                    #pragma unroll
                    for (int r = 0; r < 4; r++) ps[r] = bfbits(v[r]);
                    *(ushort4*)((bf16*)o2 + ((size_t)(bidx * NHEAD + hh) * 64 + dd) * NTOK + nn0) = p;
                }
            }
        } else {
            float* out = (float*)o0;
            #pragma unroll
            for (int mt = 0; mt < 4; mt++) {
                const int gm0 = m0 + wm + mt * 16 + kg * 4;
                #pragma unroll
                for (int r = 0; r < 4; r++)
                    out[(size_t)(gm0 + r) * NOUT + gn] = acc[mt][nt][r] + bv;
            }
        }
    }
}

// ---------- K1 template: R14 3-buffer counted-vmcnt pipeline (proven) ----------
template<int NOUT, int EPI, int BF16B>
__global__ __launch_bounds__(256) void gemm_bt16(const bf16* __restrict__ A,
                                                 const void* __restrict__ Bmv,
                                                 const float* __restrict__ bias,
                                                 void* __restrict__ o0,
                                                 void* __restrict__ o1,
                                                 void* __restrict__ o2)
{
    __shared__ alignas(16) bf16 As[3 * 4096];   // 3 K-step buffers (24KB)
    __shared__ alignas(16) bf16 Bs[3 * 4096];   // 48KB total
    const int tid  = threadIdx.x;
    const int lane = tid & 63;
    const int wv   = tid >> 6;
    const int r16  = lane & 15;
    const int kg   = lane >> 4;

    constexpr int GX  = NOUT / 128;
    constexpr int NWG = GX * 160;
    int flat = blockIdx.y * GX + blockIdx.x;
    flat = (flat & 7) * (NWG >> 3) + (flat >> 3);
    const int byy = flat / GX;
    const int bxx = flat - byy * GX;
    const int m0  = byy * 128;
    const int n0  = bxx * 128;
    const int wm  = (wv & 1) * 64;
    const int wn  = (wv >> 1) * 64;

    const bf16*  Ab   = A + (size_t)m0 * CDIM;
    const bf16*  Bb16 = (const bf16*)Bmv  + (size_t)n0 * CDIM;
    const float* Bb32 = (const float*)Bmv + (size_t)n0 * CDIM;

    const int ra0 = tid >> 2;

    f32x4 acc[4][4] = {};

    if constexpr (BF16B) {
        // T2 inverse source swizzle (conflicts 8.8M->0, R14-measured)
        const int ca_sw = (((tid & 3) ^ ((tid >> 3) & 3)) * 8);
        const bf16* gA0 = Ab   + (size_t)ra0 * CDIM + ca_sw;
        const bf16* gB0 = Bb16 + (size_t)ra0 * CDIM + ca_sw;
        const int kgs = (kg ^ ((r16 >> 1) & 3)) * 8;

        auto stage = [&](int kt, int buf) {
            const int k0 = kt * 32;
            const size_t lb = (size_t)buf * 4096;
            stage16(gA0 + k0,             &As[lb + wv * 512]);
            stage16(gA0 + 64 * CDIM + k0, &As[lb + wv * 512 + 2048]);
            stage16(gB0 + k0,             &Bs[lb + wv * 512]);
            stage16(gB0 + 64 * CDIM + k0, &Bs[lb + wv * 512 + 2048]);
        };
        auto compute = [&](int buf) {
            const size_t lb = (size_t)buf * 4096;
            short8 af[4], bfr[4];
            #pragma unroll
            for (int mt = 0; mt < 4; mt++)
                af[mt] = *(const short8*)&As[lb + (wm + mt * 16 + r16) * 32 + kgs];
            #pragma unroll
            for (int nt = 0; nt < 4; nt++)
                bfr[nt] = *(const short8*)&Bs[lb + (wn + nt * 16 + r16) * 32 + kgs];
            __builtin_amdgcn_s_setprio(1);
            #pragma unroll
            for (int mt = 0; mt < 4; mt++)
                #pragma unroll
                for (int nt = 0; nt < 4; nt++)
                    acc[mt][nt] = MFMA16(af[mt], bfr[nt], acc[mt][nt]);
            __builtin_amdgcn_s_setprio(0);
        };

        constexpr int NKT = CDIM / 32;   // 24
        stage(0, 0);
        stage(1, 1);
        for (int t = 0; t < NKT; ++t) {
            if (t < NKT - 1) { asm volatile("s_waitcnt vmcnt(4)" ::: "memory"); }
            else             { asm volatile("s_waitcnt vmcnt(0)" ::: "memory"); }
            __builtin_amdgcn_s_barrier();
            asm volatile("" ::: "memory");
            if (t + 2 < NKT) stage(t + 2, (t + 2) % 3);
            compute(t % 3);
        }
    } else {
        const int ca0 = (tid & 3) * 8;
        for (int k0 = 0; k0 < CDIM; k0 += 32) {
            short8 gb0 = ldfrag(Bb32 + (size_t)ra0        * CDIM + k0 + ca0);
            short8 gb1 = ldfrag(Bb32 + (size_t)(ra0 + 64) * CDIM + k0 + ca0);
            __syncthreads();
            stage16(Ab + (size_t)ra0        * CDIM + k0 + ca0, &As[(size_t)(wv * 64) * 8]);
            stage16(Ab + (size_t)(ra0 + 64) * CDIM + k0 + ca0, &As[(size_t)(wv * 64 + 256) * 8]);
            *(short8*)&Bs[(size_t)tid * 8]         = gb0;
            *(short8*)&Bs[(size_t)(tid + 256) * 8] = gb1;
            __syncthreads();

            short8 af[4], bfr[4];
            #pragma unroll
            for (int mt = 0; mt < 4; mt++)
                af[mt] = *(const short8*)&As[(wm + mt * 16 + r16) * 32 + kg * 8];
            #pragma unroll
            for (int nt = 0; nt < 4; nt++)
                bfr[nt] = *(const short8*)&Bs[(wn + nt * 16 + r16) * 32 + kg * 8];
            #pragma unroll
            for (int mt = 0; mt < 4; mt++)
                #pragma unroll
                for (int nt = 0; nt < 4; nt++)
                    acc[mt][nt] = MFMA16(af[mt], bfr[nt], acc[mt][nt]);
        }
    }

    gemm_epilogue<NOUT, EPI>(acc, bias, o0, o1, o2, m0, n0, wm, wn, r16, kg);
}

// ---------- K3 template: Round-4 simple 2-barrier loop (proven in 382us total) ----------
template<int NOUT, int EPI, int BF16B>
__global__ __launch_bounds__(256) void gemm_bt16_s(const bf16* __restrict__ A,
                                                   const void* __restrict__ Bmv,
                                                   const float* __restrict__ bias,
                                                   void* __restrict__ o0,
                                                   void* __restrict__ o1,
                                                   void* __restrict__ o2)
{
    __shared__ alignas(16) bf16 As[128 * 32];
    __shared__ alignas(16) bf16 Bs[128 * 32];
    const int tid  = threadIdx.x;
    const int lane = tid & 63;
    const int wv   = tid >> 6;
    const int r16  = lane & 15;
    const int kg   = lane >> 4;

    constexpr int GX  = NOUT / 128;
    constexpr int NWG = GX * 160;
    int flat = blockIdx.y * GX + blockIdx.x;
    flat = (flat & 7) * (NWG >> 3) + (flat >> 3);
    const int byy = flat / GX;
    const int bxx = flat - byy * GX;
    const int m0  = byy * 128;
    const int n0  = bxx * 128;
    const int wm  = (wv & 1) * 64;
    const int wn  = (wv >> 1) * 64;

    const bf16*  Ab   = A + (size_t)m0 * CDIM;
    const bf16*  Bb16 = (const bf16*)Bmv  + (size_t)n0 * CDIM;
    const float* Bb32 = (const float*)Bmv + (size_t)n0 * CDIM;

    const int ra0 = tid >> 2;
    const int ca0 = (tid & 3) * 8;

    bf16* lA0 = &As[(size_t)(wv * 64) * 8];
    bf16* lA1 = &As[(size_t)(wv * 64 + 256) * 8];
    bf16* lB0 = &Bs[(size_t)(wv * 64) * 8];
    bf16* lB1 = &Bs[(size_t)(wv * 64 + 256) * 8];

    f32x4 acc[4][4] = {};

    for (int k0 = 0; k0 < CDIM; k0 += 32) {
        if constexpr (BF16B) {
            __syncthreads();
            stage16(Ab   + (size_t)ra0        * CDIM + k0 + ca0, lA0);
            stage16(Ab   + (size_t)(ra0 + 64) * CDIM + k0 + ca0, lA1);
            stage16(Bb16 + (size_t)ra0        * CDIM + k0 + ca0, lB0);
            stage16(Bb16 + (size_t)(ra0 + 64) * CDIM + k0 + ca0, lB1);
            __syncthreads();
        } else {
            short8 gb0 = ldfrag(Bb32 + (size_t)ra0        * CDIM + k0 + ca0);
            short8 gb1 = ldfrag(Bb32 + (size_t)(ra0 + 64) * CDIM + k0 + ca0);
            __syncthreads();
            stage16(Ab + (size_t)ra0        * CDIM + k0 + ca0, lA0);
            stage16(Ab + (size_t)(ra0 + 64) * CDIM + k0 + ca0, lA1);
            *(short8*)&Bs[(size_t)tid * 8]         = gb0;
            *(short8*)&Bs[(size_t)(tid + 256) * 8] = gb1;
            __syncthreads();
        }

        short8 af[4], bfr[4];
        #pragma unroll
        for (int mt = 0; mt < 4; mt++)
            af[mt] = *(const short8*)&As[(wm + mt * 16 + r16) * 32 + kg * 8];
        #pragma unroll
        for (int nt = 0; nt < 4; nt++)
            bfr[nt] = *(const short8*)&Bs[(wn + nt * 16 + r16) * 32 + kg * 8];
        #pragma unroll
        for (int mt = 0; mt < 4; mt++)
            #pragma unroll
            for (int nt = 0; nt < 4; nt++)
                acc[mt][nt] = MFMA16(af[mt], bfr[nt], acc[mt][nt]);
    }

    gemm_epilogue<NOUT, EPI>(acc, bias, o0, o1, o2, m0, n0, wm, wn, r16, kg);
}

// ---------- attention: exact R12 kernel (best measured: 118-126us) ----------
#define ATTN_NWG (768 * 10)
__global__ __launch_bounds__(256, 4) void attn_kernel(const bf16* __restrict__ q_ws,
                                                      const bf16* __restrict__ k_ws,
                                                      const bf16* __restrict__ vt_ws,
                                                      bf16* __restrict__ attn,
                                                      const int* __restrict__ numt_p)
{
    __shared__ alignas(16) float S[32 * 320];
    int num_t = 64;
    if (numt_p) {
        int v = *numt_p;
        float f = __int_as_float(v);
        if (v >= 1 && v <= 319) num_t = v;
        else if (f >= 1.f && f <= 319.f) num_t = (int)f;
    }
    if (num_t <= 0 || num_t > NTOK || (num_t & 31)) num_t = 64;

    const int tid  = threadIdx.x;
    const int lane = tid & 63;
    const int w    = tid >> 6;
    const int r16  = lane & 15;
    const int kg   = lane >> 4;

    int blk = blockIdx.x;
    blk = (blk & 7) * (ATTN_NWG / 8) + (blk >> 3);
    const int bh  = blk / 10;
    const int qt  = blk - bh * 10;
    const int b   = bh / NHEAD;
    const int h   = bh - b * NHEAD;
    const int q0  = qt * 32;
    const int nk  = (q0 + 32 <= num_t) ? num_t : NTOK;
    const int nk16 = nk >> 4;

    const bf16* qp = q_ws  + (size_t)bh * NTOK * 64;
    const bf16* kp = k_ws  + (size_t)bh * NTOK * 64;
    const bf16* vp = vt_ws + (size_t)bh * 64 * NTOK;

    // ---- Phase 1: S = (Q K^T) * scale ----
    short8 qf[2][2];
    #pragma unroll
    for (int ks = 0; ks < 2; ks++)
        #pragma unroll
        for (int mt = 0; mt < 2; mt++)
            qf[ks][mt] = ldfrag(qp + (size_t)(q0 + mt * 16 + r16) * 64 + ks * 32 + kg * 8);

    const float scale = 0.125f;   // 1/sqrt(64)
    auto p1body = [&](int nt) {
        f32x4 a0 = {}, a1 = {};
        #pragma unroll
        for (int ks = 0; ks < 2; ks++) {
            short8 kf = ldfrag(kp + (size_t)(nt * 16 + r16) * 64 + ks * 32 + kg * 8);
            a0 = MFMA16(qf[ks][0], kf, a0);
            a1 = MFMA16(qf[ks][1], kf, a1);
        }
        const int col = nt * 16 + r16;
        #pragma unroll
        for (int r = 0; r < 4; r++) {
            const int ro  = kg * 4 + r;
            const int swz = (ro & 7) << 2;
            S[ro * 320        + (col ^ swz)] = a0[r] * scale;
            S[(16 + ro) * 320 + (col ^ swz)] = a1[r] * scale;
        }
    };
    if (nk16 == 20) {
        #pragma unroll
        for (int it = 0; it < 5; it++) p1body(w + it * 4);
    } else {
        for (int nt = w; nt < nk16; nt += 4) p1body(nt);
    }
    __syncthreads();

    // ---- Phase 2: row softmax with bf16-P overlay (hazard analysis in R10-R12) ----
    {
        const int row = tid >> 3;
        const int sub = tid & 7;
        const int swzw = (row & 7) << 2;
        const int swzh = (row & 7) << 3;
        float* Sr = S + row * 320;
        bf16*  Pr = (bf16*)Sr;
        float mx = -1e30f;
        for (int c = sub * 4; c < nk; c += 32) {
            float4 t = *(float4*)&Sr[c ^ swzw];
            mx = fmaxf(mx, fmaxf(fmaxf(t.x, t.y), fmaxf(t.z, t.w)));
        }
        #pragma unroll
        for (int m = 1; m < 8; m <<= 1) mx = fmaxf(mx, __shfl_xor(mx, m));
        float sum = 0.f;
        for (int c = sub * 4; c < nk; c += 32) {
            float4 t = *(float4*)&Sr[c ^ swzw];
            t.x = __expf(t.x - mx); t.y = __expf(t.y - mx);
            t.z = __expf(t.z - mx); t.w = __expf(t.w - mx);
            sum += t.x + t.y + t.z + t.w;
            ushort4 p;
            p.x = bfbits(t.x); p.y = bfbits(t.y); p.z = bfbits(t.z); p.w = bfbits(t.w);
            *(ushort4*)&Pr[c ^ swzh] = p;
        }
        #pragma unroll
        for (int m = 1; m < 8; m <<= 1) sum += __shfl_xor(sum, m);
        if (sub == 0) Sr[316 ^ swzw] = 1.0f / sum;
    }
    __syncthreads();

    // ---- Phase 3: O = P @ V ----
    const int mt  = w & 1;
    const int ntb = w >> 1;
    const int prow = mt * 16 + r16;
    const bf16* Pbr = (const bf16*)(S + prow * 320);
    const int pswzh = (prow & 7) << 3;
    f32x4 o[2] = {};
    auto p3body = [&](int ks) {
        short8 af = *(const short8*)&Pbr[(ks * 32 + kg * 8) ^ pswzh];
        #pragma unroll
        for (int i = 0; i < 2; i++) {
            const int nt = ntb + i * 2;
            short8 vf = ldfrag(vp + (size_t)(nt * 16 + r16) * NTOK + ks * 32 + kg * 8);
            o[i] = MFMA16(af, vf, o[i]);
        }
    };
    if (nk == NTOK) {
        #pragma unroll
        for (int ks = 0; ks < 10; ks++) p3body(ks);
    } else {
        for (int ks = 0; ks < (nk >> 5); ks++) p3body(ks);
    }
    #pragma unroll
    for (int i = 0; i < 2; i++) {
        const int nt = ntb + i * 2;
        const int dd = nt * 16 + r16;
        #pragma unroll
        for (int r = 0; r < 4; r++) {
            const int qrow  = mt * 16 + kg * 4 + r;
            const float invs = S[qrow * 320 + (316 ^ ((qrow & 7) << 2))];
            const float val = o[i][r] * invs;
            const int token = q0 + qrow;
            attn[(((size_t)b * NTOK + token) * NHEAD + h) * 64 + dd] = __float2bfloat16(val);
        }
    }
}

extern "C" void kernel_launch(void* const* d_in, const int* in_sizes, int n_in,
                              void* d_out, int out_size, void* d_ws, size_t ws_size,
                              hipStream_t stream)
{
    float* out = (float*)d_out;

    const float *x = nullptr, *w_qkv = nullptr, *b_qkv = nullptr,
                *w_proj = nullptr, *b_proj = nullptr;
    const int* numt_p = nullptr;
    for (int i = 0; i < n_in; i++) {
        switch (in_sizes[i]) {
            case 15728640: x      = (const float*)d_in[i]; break;  // (64,320,768)
            case 1769472:  w_qkv  = (const float*)d_in[i]; break;  // (2304,768)
            case 2304:     b_qkv  = (const float*)d_in[i]; break;  // (2304,)
            case 589824:   w_proj = (const float*)d_in[i]; break;  // (768,768)
            case 768:      b_proj = (const float*)d_in[i]; break;  // (768,)
            case 1:        if (!numt_p) numt_p = (const int*)d_in[i]; break;
            default: break;
        }
    }
    if (!x || !w_qkv || !b_qkv || !w_proj || !b_proj) return;

    const size_t per      = (size_t)64 * NHEAD * NTOK * 64;  // 15,728,640 elems
    const size_t wq_elems = (size_t)2304 * 768;              // 1,769,472
    const size_t wp_elems = (size_t)768 * 768;               //   589,824
    const size_t base_need = 4 * per * sizeof(bf16);               // 125,829,120
    const size_t full_need = base_need + (wq_elems + wp_elems) * sizeof(bf16); // +4.7MB
    if (ws_size < base_need) return;
    const bool full = ws_size >= full_need;

    bf16* q_ws  = (bf16*)d_ws;
    bf16* k_ws  = q_ws  + per;
    bf16* vt_ws = k_ws  + per;
    bf16* attn  = vt_ws + per;   // doubles as x_bf16 (dead once K2 writes attn)
    bf16* x16   = attn;          // exact fit: per elems
    bf16* wq16  = attn + per;    // only touched when `full`
    bf16* wp16  = wq16 + wq_elems;

    // K0: fused f32->bf16 conversions (one launch)
    if (full)
        cvt3_kernel<<<2048, 256, 0, stream>>>(x, x16, (int)(per / 8),
                                              w_qkv, wq16, (int)(wq_elems / 8),
                                              w_proj, wp16, (int)(wp_elems / 8));
    else
        cvt3_kernel<<<2048, 256, 0, stream>>>(x, x16, (int)(per / 8),
                                              x, x16, 0, x, x16, 0);

    // K1: qkv = x @ w_qkv^T + b_qkv, scattered to Q,K,(V^T)  [3-buf pipeline]
    if (full)
        gemm_bt16<2304, 0, 1><<<dim3(18, 160), 256, 0, stream>>>(
            x16, wq16, b_qkv, q_ws, k_ws, vt_ws);
    else
        gemm_bt16<2304, 0, 0><<<dim3(18, 160), 256, 0, stream>>>(
            x16, w_qkv, b_qkv, q_ws, k_ws, vt_ws);

    // K2: attention  [R12 exact]
    attn_kernel<<<ATTN_NWG, 256, 0, stream>>>(q_ws, k_ws, vt_ws, attn, numt_p);

    // K3: out = attn @ w_proj^T + b_proj (f32 stores)  [simple 2-barrier]
    if (full)
        gemm_bt16_s<768, 1, 1><<<dim3(6, 160), 256, 0, stream>>>(
            attn, wp16, b_proj, out, nullptr, nullptr);
    else
        gemm_bt16_s<768, 1, 0><<<dim3(6, 160), 256, 0, stream>>>(
            attn, w_proj, b_proj, out, nullptr, nullptr);
}

// Round 12
// 377.841 us; speedup vs baseline: 1.1175x; 1.0251x over previous
//
#include <hip/hip_runtime.h>
#include <hip/hip_bf16.h>

// Problem: B=64, N=320, C=768, H=12, D=64, num_t=64 (runtime-read), num_s=256.
// ESTABLISHED: inputs f32, output f32, ws>=126MB, d_in dict order.
// LEDGER: R9 GEMM rebuild 195->~130. R10/R11 attn XCD swizzle (FETCH 261->46MB,
//   time flat => attn latency/serial-bound, not BW). R12 attn 4blk/CU ~121
//   (attn local floor; R17 occupancy 82% made it WORSE). R13/R14: counted-vmcnt
//   on 128^2 2-phase = NULL (regime-gate confirmed: T4 needs deep structure).
//   R15/R16 V-prefetch defeated by compiler. R18 consolidation: totals flat
//   382-390 => K1's 2-phase 128^2 structure (599 TF, Mfma 25%) is the only
//   >20us lever left.
// R19: K1 -> 256^2/BK=64/8-wave/128KB-LDS deep pipeline (2-buf, counted
//   vmcnt(8), T2 both-sides swizzle, T5 setprio). Bench infra failed
//   ("container failed twice" — same signature as R2/R7, both passed on
//   resubmit). Re-audit: barrier-uniform, vmcnt ledger exact, swizzle
//   round-trip verified, WAR barrier-protected.
// R20 (this round): RESUBMIT of R19; only change __launch_bounds__(512,2)
//   (explicitly pins VGPR<=256 so 8-wave residency is guaranteed).

typedef __attribute__((ext_vector_type(8))) short short8;
typedef __attribute__((ext_vector_type(4))) float f32x4;
typedef __hip_bfloat16 bf16;

#define NTOK 320
#define CDIM 768
#define NHEAD 12
#define MFMA16(a,b,c) __builtin_amdgcn_mfma_f32_16x16x32_bf16((a),(b),(c),0,0,0)

__device__ __forceinline__ unsigned short bfbits(float v) {
    bf16 h = __float2bfloat16(v);
    unsigned short u; __builtin_memcpy(&u, &h, 2);
    return u;
}

__device__ __forceinline__ short8 ldfrag(const bf16* p) { return *(const short8*)p; }
__device__ __forceinline__ short8 ldfrag(const float* p) {
    float4 a = *(const float4*)p;
    float4 b = *(const float4*)(p + 4);
    short8 r;
    r[0]=(short)bfbits(a.x); r[1]=(short)bfbits(a.y); r[2]=(short)bfbits(a.z); r[3]=(short)bfbits(a.w);
    r[4]=(short)bfbits(b.x); r[5]=(short)bfbits(b.y); r[6]=(short)bfbits(b.z); r[7]=(short)bfbits(b.w);
    return r;
}

// async global->LDS, 16B per lane. LDS dest must be wave-uniform base; HW adds lane*16.
__device__ __forceinline__ void stage16(const bf16* g, bf16* l) {
    __builtin_amdgcn_global_load_lds(
        (const __attribute__((address_space(1))) void*)g,
        (__attribute__((address_space(3))) void*)l, 16, 0, 0);
}

// fused f32 -> bf16 bulk convert over up to 3 segments, 8 elems/thread/iter
__global__ __launch_bounds__(256) void cvt3_kernel(const float* __restrict__ s0, bf16* __restrict__ d0, int n0,
                                                   const float* __restrict__ s1, bf16* __restrict__ d1, int n1,
                                                   const float* __restrict__ s2, bf16* __restrict__ d2, int n2)
{
    const int ntot = n0 + n1 + n2;
    int i = blockIdx.x * 256 + threadIdx.x;
    const int stride = gridDim.x * 256;
    for (; i < ntot; i += stride) {
        const float* s; bf16* d; int j = i;
        if (j < n0)              { s = s0; d = d0; }
        else if ((j -= n0) < n1) { s = s1; d = d1; }
        else                     { j -= n1; s = s2; d = d2; }
        const float4 a = ((const float4*)s)[2 * (size_t)j];
        const float4 b = ((const float4*)s)[2 * (size_t)j + 1];
        short8 r;
        r[0]=(short)bfbits(a.x); r[1]=(short)bfbits(a.y); r[2]=(short)bfbits(a.z); r[3]=(short)bfbits(a.w);
        r[4]=(short)bfbits(b.x); r[5]=(short)bfbits(b.y); r[6]=(short)bfbits(b.z); r[7]=(short)bfbits(b.w);
        ((short8*)d)[j] = r;
    }
}

// ---------- K1: 256^2 deep-pipelined GEMM (bf16 A,B), EPI=qkv scatter ----------
// A: 20480x768 bf16 (x16). Bm: 2304x768 bf16 (wq16). Grid dim3(9,80), 512 thr.
__global__ __launch_bounds__(512, 2) void gemm256_k1(const bf16* __restrict__ A,
                                                     const bf16* __restrict__ Bm,
                                                     const float* __restrict__ bias,
                                                     void* __restrict__ o0,
                                                     void* __restrict__ o1,
                                                     void* __restrict__ o2)
{
    __shared__ alignas(16) bf16 As[2][256 * 64];   // 64KB
    __shared__ alignas(16) bf16 Bs[2][256 * 64];   // 64KB -> 128KB total, 1 blk/CU
    const int tid    = threadIdx.x;                // 0..511
    const int lane   = tid & 63;
    const int wv     = tid >> 6;                   // 0..7
    const int r16    = lane & 15;
    const int kg     = lane >> 4;                  // 0..3
    const int warp_m = wv >> 2;                    // 0..1
    const int warp_n = wv & 3;                     // 0..3

    constexpr int GX  = 2304 / 256;                // 9
    constexpr int GY  = 20480 / 256;               // 80
    constexpr int NWG = GX * GY;                   // 720 (%8==0)
    int flat = blockIdx.y * GX + blockIdx.x;
    flat = (flat & 7) * (NWG / 8) + (flat >> 3);   // bijective XCD swizzle
    const int byy = flat / GX;
    const int bxx = flat - byy * GX;
    const int m0  = byy * 256;
    const int n0  = bxx * 256;

    // staging constants: thread t covers slot (row = j*64 + wv*8 + (lane>>3),
    // chunk = lane&7); slot holds GLOBAL chunk (lane&7)^(lane>>3) (row&7 ==
    // lane>>3 since j*64+wv*8 is a multiple of 8) -> inverse T2 swizzle.
    const int srl  = wv * 8 + (lane >> 3);                  // 0..63
    const int gcol = ((lane & 7) ^ (lane >> 3)) * 8;        // elems
    const bf16* gA = A  + (size_t)(m0 + srl) * CDIM + gcol;
    const bf16* gB = Bm + (size_t)(n0 + srl) * CDIM + gcol;
    const int ldsb = wv * 512;                              // elems; + j*4096

    auto stageTile = [&](int kt, int buf) {
        const int k0 = kt * 64;
        #pragma unroll
        for (int j = 0; j < 4; j++)
            stage16(gA + (size_t)j * 64 * CDIM + k0, &As[buf][j * 4096 + ldsb]);
        #pragma unroll
        for (int j = 0; j < 4; j++)
            stage16(gB + (size_t)j * 64 * CDIM + k0, &Bs[buf][j * 4096 + ldsb]);
    };

    // read constants: fragment (row, ks, kg) -> chunk (ks*4+kg)^(row&7),
    // row&7 == r16&7 for all fragment rows (bases are multiples of 16).
    const int arow = warp_m * 128 + r16;       // + m*16
    const int brow = warp_n * 64  + r16;       // + n*16
    const int csw0 = ((0 * 4 + kg) ^ (r16 & 7)) * 8;
    const int csw1 = ((1 * 4 + kg) ^ (r16 & 7)) * 8;

    f32x4 acc[8][4] = {};

    constexpr int NKT = CDIM / 64;   // 12
    stageTile(0, 0);                 // 8 issues
    stageTile(1, 1);                 // 8 issues (16 outstanding)
    for (int kt = 0; kt < NKT; ++kt) {
        const int buf = kt & 1;
        // tile kt = oldest 8 of <=16 outstanding; keep kt+1 in flight
        if (kt < NKT - 1) { asm volatile("s_waitcnt vmcnt(8)" ::: "memory"); }
        else              { asm volatile("s_waitcnt vmcnt(0)" ::: "memory"); }
        __builtin_amdgcn_s_barrier();
        asm volatile("" ::: "memory");
        #pragma unroll
        for (int ks = 0; ks < 2; ks++) {
            const int csw = ks ? csw1 : csw0;
            short8 af[8], bfm[4];
            #pragma unroll
            for (int m = 0; m < 8; m++)
                af[m] = *(const short8*)&As[buf][(arow + m * 16) * 64 + csw];
            #pragma unroll
            for (int n = 0; n < 4; n++)
                bfm[n] = *(const short8*)&Bs[buf][(brow + n * 16) * 64 + csw];
            __builtin_amdgcn_s_setprio(1);
            #pragma unroll
            for (int m = 0; m < 8; m++)
                #pragma unroll
                for (int n = 0; n < 4; n++)
                    acc[m][n] = MFMA16(af[m], bfm[n], acc[m][n]);
            __builtin_amdgcn_s_setprio(0);
        }
        // all this wave's ds_reads are register-complete here (MFMA deps);
        // explicit lgkmcnt(0) pins loads above the barrier.
        asm volatile("s_waitcnt lgkmcnt(0)" ::: "memory");
        __builtin_amdgcn_s_barrier();        // all waves done reading buf
        if (kt + 2 < NKT) stageTile(kt + 2, buf);   // WAR-safe overwrite
    }

    // Epilogue: qkv scatter. C/D layout: col=r16 (in gn), row=kg*4+r (in gm).
    #pragma unroll
    for (int n = 0; n < 4; n++) {
        const int gn = n0 + warp_n * 64 + n * 16 + r16;
        const float bv = bias[gn];
        const int which = gn / CDIM;
        const int rem   = gn - which * CDIM;
        const int hh    = rem >> 6;
        const int dd    = rem & 63;
        #pragma unroll
        for (int m = 0; m < 8; m++) {
            const int gm0  = m0 + warp_m * 128 + m * 16 + kg * 4;  // 4-aligned
            const int bidx = gm0 / NTOK;                           // 320%4==0
            const int nn0  = gm0 - bidx * NTOK;
            float v[4];
            #pragma unroll
            for (int r = 0; r < 4; r++) v[r] = acc[m][n][r] + bv;
            if (which == 0) {
                bf16* q = (bf16*)o0 + ((size_t)(bidx * NHEAD + hh) * NTOK + nn0) * 64 + dd;
                #pragma unroll
                for (int r = 0; r < 4; r++) q[(size_t)r * 64] = __float2bfloat16(v[r]);
            } else if (which == 1) {
                bf16* k = (bf16*)o1 + ((size_t)(bidx * NHEAD + hh) * NTOK + nn0) * 64 + dd;
                #pragma unroll
                for (int r = 0; r < 4; r++) k[(size_t)r * 64] = __float2bfloat16(v[r]);
            } else {
                ushort4 p;
                unsigned short* ps = (unsigned short*)&p;
                #pragma unroll
                for (int r = 0; r < 4; r++) ps[r] = bfbits(v[r]);
                *(ushort4*)((bf16*)o2 + ((size_t)(bidx * NHEAD + hh) * 64 + dd) * NTOK + nn0) = p;
            }
        }
    }
}

// ---------- simple 2-barrier 128^2 GEMM template (K3 + insurance K1) ----------
template<int NOUT, int EPI, int BF16B>
__global__ __launch_bounds__(256) void gemm_bt16_s(const bf16* __restrict__ A,
                                                   const void* __restrict__ Bmv,
                                                   const float* __restrict__ bias,
                                                   void* __restrict__ o0,
                                                   void* __restrict__ o1,
                                                   void* __restrict__ o2)
{
    __shared__ alignas(16) bf16 As[128 * 32];
    __shared__ alignas(16) bf16 Bs[128 * 32];
    const int tid  = threadIdx.x;
    const int lane = tid & 63;
    const int wv   = tid >> 6;
    const int r16  = lane & 15;
    const int kg   = lane >> 4;

    constexpr int GX  = NOUT / 128;
    constexpr int NWG = GX * 160;
    int flat = blockIdx.y * GX + blockIdx.x;
    flat = (flat & 7) * (NWG >> 3) + (flat >> 3);
    const int byy = flat / GX;
    const int bxx = flat - byy * GX;
    const int m0  = byy * 128;
    const int n0  = bxx * 128;
    const int wm  = (wv & 1) * 64;
    const int wn  = (wv >> 1) * 64;

    const bf16*  Ab   = A + (size_t)m0 * CDIM;
    const bf16*  Bb16 = (const bf16*)Bmv  + (size_t)n0 * CDIM;
    const float* Bb32 = (const float*)Bmv + (size_t)n0 * CDIM;

    const int ra0 = tid >> 2;
    const int ca0 = (tid & 3) * 8;

    bf16* lA0 = &As[(size_t)(wv * 64) * 8];
    bf16* lA1 = &As[(size_t)(wv * 64 + 256) * 8];
    bf16* lB0 = &Bs[(size_t)(wv * 64) * 8];
    bf16* lB1 = &Bs[(size_t)(wv * 64 + 256) * 8];

    f32x4 acc[4][4] = {};

    for (int k0 = 0; k0 < CDIM; k0 += 32) {
        if constexpr (BF16B) {
            __syncthreads();
            stage16(Ab   + (size_t)ra0        * CDIM + k0 + ca0, lA0);
            stage16(Ab   + (size_t)(ra0 + 64) * CDIM + k0 + ca0, lA1);
            stage16(Bb16 + (size_t)ra0        * CDIM + k0 + ca0, lB0);
            stage16(Bb16 + (size_t)(ra0 + 64) * CDIM + k0 + ca0, lB1);
            __syncthreads();
        } else {
            short8 gb0 = ldfrag(Bb32 + (size_t)ra0        * CDIM + k0 + ca0);
            short8 gb1 = ldfrag(Bb32 + (size_t)(ra0 + 64) * CDIM + k0 + ca0);
            __syncthreads();
            stage16(Ab + (size_t)ra0        * CDIM + k0 + ca0, lA0);
            stage16(Ab + (size_t)(ra0 + 64) * CDIM + k0 + ca0, lA1);
            *(short8*)&Bs[(size_t)tid * 8]         = gb0;
            *(short8*)&Bs[(size_t)(tid + 256) * 8] = gb1;
            __syncthreads();
        }

        short8 af[4], bfr[4];
        #pragma unroll
        for (int mt = 0; mt < 4; mt++)
            af[mt] = *(const short8*)&As[(wm + mt * 16 + r16) * 32 + kg * 8];
        #pragma unroll
        for (int nt = 0; nt < 4; nt++)
            bfr[nt] = *(const short8*)&Bs[(wn + nt * 16 + r16) * 32 + kg * 8];
        #pragma unroll
        for (int mt = 0; mt < 4; mt++)
            #pragma unroll
            for (int nt = 0; nt < 4; nt++)
                acc[mt][nt] = MFMA16(af[mt], bfr[nt], acc[mt][nt]);
    }

    #pragma unroll
    for (int nt = 0; nt < 4; nt++) {
        const int gn = n0 + wn + nt * 16 + r16;
        const float bv = bias[gn];
        if (EPI == 0) {
            const int which = gn / CDIM;
            const int rem   = gn - which * CDIM;
            const int hh    = rem >> 6;
            const int dd    = rem & 63;
            #pragma unroll
            for (int mt = 0; mt < 4; mt++) {
                const int gm0  = m0 + wm + mt * 16 + kg * 4;
                const int bidx = gm0 / NTOK;
                const int nn0  = gm0 - bidx * NTOK;
                float v[4];
                #pragma unroll
                for (int r = 0; r < 4; r++) v[r] = acc[mt][nt][r] + bv;
                if (which == 0) {
                    bf16* q = (bf16*)o0 + ((size_t)(bidx * NHEAD + hh) * NTOK + nn0) * 64 + dd;
                    #pragma unroll
                    for (int r = 0; r < 4; r++) q[(size_t)r * 64] = __float2bfloat16(v[r]);
                } else if (which == 1) {
                    bf16* k = (bf16*)o1 + ((size_t)(bidx * NHEAD + hh) * NTOK + nn0) * 64 + dd;
                    #pragma unroll
                    for (int r = 0; r < 4; r++) k[(size_t)r * 64] = __float2bfloat16(v[r]);
                } else {
                    ushort4 p;
                    unsigned short* ps = (unsigned short*)&p;
                    #pragma unroll
                    for (int r = 0; r < 4; r++) ps[r] = bfbits(v[r]);
                    *(ushort4*)((bf16*)o2 + ((size_t)(bidx * NHEAD + hh) * 64 + dd) * NTOK + nn0) = p;
                }
            }
        } else {
            float* out = (float*)o0;
            #pragma unroll
            for (int mt = 0; mt < 4; mt++) {
                const int gm0 = m0 + wm + mt * 16 + kg * 4;
                #pragma unroll
                for (int r = 0; r < 4; r++)
                    out[(size_t)(gm0 + r) * NOUT + gn] = acc[mt][nt][r] + bv;
            }
        }
    }
}

// ---------- attention: exact R12 kernel (best measured: 118-126us) ----------
#define ATTN_NWG (768 * 10)
__global__ __launch_bounds__(256, 4) void attn_kernel(const bf16* __restrict__ q_ws,
                                                      const bf16* __restrict__ k_ws,
                                                      const bf16* __restrict__ vt_ws,
                                                      bf16* __restrict__ attn,
                                                      const int* __restrict__ numt_p)
{
    __shared__ alignas(16) float S[32 * 320];
    int num_t = 64;
    if (numt_p) {
        int v = *numt_p;
        float f = __int_as_float(v);
        if (v >= 1 && v <= 319) num_t = v;
        else if (f >= 1.f && f <= 319.f) num_t = (int)f;
    }
    if (num_t <= 0 || num_t > NTOK || (num_t & 31)) num_t = 64;

    const int tid  = threadIdx.x;
    const int lane = tid & 63;
    const int w    = tid >> 6;
    const int r16  = lane & 15;
    const int kg   = lane >> 4;

    int blk = blockIdx.x;
    blk = (blk & 7) * (ATTN_NWG / 8) + (blk >> 3);
    const int bh  = blk / 10;
    const int qt  = blk - bh * 10;
    const int b   = bh / NHEAD;
    const int h   = bh - b * NHEAD;
    const int q0  = qt * 32;
    const int nk  = (q0 + 32 <= num_t) ? num_t : NTOK;
    const int nk16 = nk >> 4;

    const bf16* qp = q_ws  + (size_t)bh * NTOK * 64;
    const bf16* kp = k_ws  + (size_t)bh * NTOK * 64;
    const bf16* vp = vt_ws + (size_t)bh * 64 * NTOK;

    short8 qf[2][2];
    #pragma unroll
    for (int ks = 0; ks < 2; ks++)
        #pragma unroll
        for (int mt = 0; mt < 2; mt++)
            qf[ks][mt] = ldfrag(qp + (size_t)(q0 + mt * 16 + r16) * 64 + ks * 32 + kg * 8);

    const float scale = 0.125f;   // 1/sqrt(64)
    auto p1body = [&](int nt) {
        f32x4 a0 = {}, a1 = {};
        #pragma unroll
        for (int ks = 0; ks < 2; ks++) {
            short8 kf = ldfrag(kp + (size_t)(nt * 16 + r16) * 64 + ks * 32 + kg * 8);
            a0 = MFMA16(qf[ks][0], kf, a0);
            a1 = MFMA16(qf[ks][1], kf, a1);
        }
        const int col = nt * 16 + r16;
        #pragma unroll
        for (int r = 0; r < 4; r++) {
            const int ro  = kg * 4 + r;
            const int swz = (ro & 7) << 2;
            S[ro * 320        + (col ^ swz)] = a0[r] * scale;
            S[(16 + ro) * 320 + (col ^ swz)] = a1[r] * scale;
        }
    };
    if (nk16 == 20) {
        #pragma unroll
        for (int it = 0; it < 5; it++) p1body(w + it * 4);
    } else {
        for (int nt = w; nt < nk16; nt += 4) p1body(nt);
    }
    __syncthreads();

    {
        const int row = tid >> 3;
        const int sub = tid & 7;
        const int swzw = (row & 7) << 2;
        const int swzh = (row & 7) << 3;
        float* Sr = S + row * 320;
        bf16*  Pr = (bf16*)Sr;
        float mx = -1e30f;
        for (int c = sub * 4; c < nk; c += 32) {
            float4 t = *(float4*)&Sr[c ^ swzw];
            mx = fmaxf(mx, fmaxf(fmaxf(t.x, t.y), fmaxf(t.z, t.w)));
        }
        #pragma unroll
        for (int m = 1; m < 8; m <<= 1) mx = fmaxf(mx, __shfl_xor(mx, m));
        float sum = 0.f;
        for (int c = sub * 4; c < nk; c += 32) {
            float4 t = *(float4*)&Sr[c ^ swzw];
            t.x = __expf(t.x - mx); t.y = __expf(t.y - mx);
            t.z = __expf(t.z - mx); t.w = __expf(t.w - mx);
            sum += t.x + t.y + t.z + t.w;
            ushort4 p;
            p.x = bfbits(t.x); p.y = bfbits(t.y); p.z = bfbits(t.z); p.w = bfbits(t.w);
            *(ushort4*)&Pr[c ^ swzh] = p;
        }
        #pragma unroll
        for (int m = 1; m < 8; m <<= 1) sum += __shfl_xor(sum, m);
        if (sub == 0) Sr[316 ^ swzw] = 1.0f / sum;
    }
    __syncthreads();

    const int mt  = w & 1;
    const int ntb = w >> 1;
    const int prow = mt * 16 + r16;
    const bf16* Pbr = (const bf16*)(S + prow * 320);
    const int pswzh = (prow & 7) << 3;
    f32x4 o[2] = {};
    auto p3body = [&](int ks) {
        short8 af = *(const short8*)&Pbr[(ks * 32 + kg * 8) ^ pswzh];
        #pragma unroll
        for (int i = 0; i < 2; i++) {
            const int nt = ntb + i * 2;
            short8 vf = ldfrag(vp + (size_t)(nt * 16 + r16) * NTOK + ks * 32 + kg * 8);
            o[i] = MFMA16(af, vf, o[i]);
        }
    };
    if (nk == NTOK) {
        #pragma unroll
        for (int ks = 0; ks < 10; ks++) p3body(ks);
    } else {
        for (int ks = 0; ks < (nk >> 5); ks++) p3body(ks);
    }
    #pragma unroll
    for (int i = 0; i < 2; i++) {
        const int nt = ntb + i * 2;
        const int dd = nt * 16 + r16;
        #pragma unroll
        for (int r = 0; r < 4; r++) {
            const int qrow  = mt * 16 + kg * 4 + r;
            const float invs = S[qrow * 320 + (316 ^ ((qrow & 7) << 2))];
            const float val = o[i][r] * invs;
            const int token = q0 + qrow;
            attn[(((size_t)b * NTOK + token) * NHEAD + h) * 64 + dd] = __float2bfloat16(val);
        }
    }
}

extern "C" void kernel_launch(void* const* d_in, const int* in_sizes, int n_in,
                              void* d_out, int out_size, void* d_ws, size_t ws_size,
                              hipStream_t stream)
{
    float* out = (float*)d_out;

    const float *x = nullptr, *w_qkv = nullptr, *b_qkv = nullptr,
                *w_proj = nullptr, *b_proj = nullptr;
    const int* numt_p = nullptr;
    for (int i = 0; i < n_in; i++) {
        switch (in_sizes[i]) {
            case 15728640: x      = (const float*)d_in[i]; break;  // (64,320,768)
            case 1769472:  w_qkv  = (const float*)d_in[i]; break;  // (2304,768)
            case 2304:     b_qkv  = (const float*)d_in[i]; break;  // (2304,)
            case 589824:   w_proj = (const float*)d_in[i]; break;  // (768,768)
            case 768:      b_proj = (const float*)d_in[i]; break;  // (768,)
            case 1:        if (!numt_p) numt_p = (const int*)d_in[i]; break;
            default: break;
        }
    }
    if (!x || !w_qkv || !b_qkv || !w_proj || !b_proj) return;

    const size_t per      = (size_t)64 * NHEAD * NTOK * 64;  // 15,728,640 elems
    const size_t wq_elems = (size_t)2304 * 768;              // 1,769,472
    const size_t wp_elems = (size_t)768 * 768;               //   589,824
    const size_t base_need = 4 * per * sizeof(bf16);               // 125,829,120
    const size_t full_need = base_need + (wq_elems + wp_elems) * sizeof(bf16); // +4.7MB
    if (ws_size < base_need) return;
    const bool full = ws_size >= full_need;

    bf16* q_ws  = (bf16*)d_ws;
    bf16* k_ws  = q_ws  + per;
    bf16* vt_ws = k_ws  + per;
    bf16* attn  = vt_ws + per;   // doubles as x_bf16 (dead once K2 writes attn)
    bf16* x16   = attn;          // exact fit: per elems
    bf16* wq16  = attn + per;    // only touched when `full`
    bf16* wp16  = wq16 + wq_elems;

    // K0: fused f32->bf16 conversions (one launch)
    if (full)
        cvt3_kernel<<<2048, 256, 0, stream>>>(x, x16, (int)(per / 8),
                                              w_qkv, wq16, (int)(wq_elems / 8),
                                              w_proj, wp16, (int)(wp_elems / 8));
    else
        cvt3_kernel<<<2048, 256, 0, stream>>>(x, x16, (int)(per / 8),
                                              x, x16, 0, x, x16, 0);

    // K1: qkv = x @ w_qkv^T + b_qkv, scattered to Q,K,(V^T)
    if (full)
        gemm256_k1<<<dim3(9, 80), 512, 0, stream>>>(
            x16, wq16, b_qkv, q_ws, k_ws, vt_ws);
    else
        gemm_bt16_s<2304, 0, 0><<<dim3(18, 160), 256, 0, stream>>>(
            x16, w_qkv, b_qkv, q_ws, k_ws, vt_ws);

    // K2: attention  [R12 exact]
    attn_kernel<<<ATTN_NWG, 256, 0, stream>>>(q_ws, k_ws, vt_ws, attn, numt_p);

    // K3: out = attn @ w_proj^T + b_proj (f32 stores)  [simple 2-barrier]
    if (full)
        gemm_bt16_s<768, 1, 1><<<dim3(6, 160), 256, 0, stream>>>(
            attn, wp16, b_proj, out, nullptr, nullptr);
    else
        gemm_bt16_s<768, 1, 0><<<dim3(6, 160), 256, 0, stream>>>(
            attn, w_proj, b_proj, out, nullptr, nullptr);
}

// Round 13
// 369.733 us; speedup vs baseline: 1.1420x; 1.0219x over previous
//
#include <hip/hip_runtime.h>
#include <hip/hip_bf16.h>

// Problem: B=64, N=320, C=768, H=12, D=64, num_t=64 (runtime-read), num_s=256.
// ESTABLISHED: inputs f32, output f32, ws>=126MB, d_in dict order.
// LEDGER: R9 GEMM rebuild 195->~130. R10/R11 attn XCD swizzle (attn is
//   latency/serial-bound, not BW). R12 attn 4blk/CU ~121 (attn local floor;
//   R17 2x-occupancy made it worse). R13/R14 counted-vmcnt on 128^2 2-phase =
//   NULL. R15/R16 V-prefetch defeated by compiler. R18 consolidation: totals
//   flat 382-390. R19/R20: K1 -> 256^2/BK=64 2-deep pipeline: rocprof row 139us
//   (replay-inflated: cold-L2 refetch per counter pass) but BENCH TOTAL 377.8
//   = best ever (-9.5 vs R18 with everything else identical) => in-graph K1
//   ~105-115; 256^2 kept. FETCH 72->60MB, conflicts 0.
// R21 (this round): K3 -> the SAME verified gemm256 template (parameter change
//   only: NOUT=768 -> grid 3x80=240 blocks, %8 bijective; EPI=1 f32 stores).
//   No sync-structure edit. K1/attn/cvt byte-stable.

typedef __attribute__((ext_vector_type(8))) short short8;
typedef __attribute__((ext_vector_type(4))) float f32x4;
typedef __hip_bfloat16 bf16;

#define NTOK 320
#define CDIM 768
#define NHEAD 12
#define MFMA16(a,b,c) __builtin_amdgcn_mfma_f32_16x16x32_bf16((a),(b),(c),0,0,0)

__device__ __forceinline__ unsigned short bfbits(float v) {
    bf16 h = __float2bfloat16(v);
    unsigned short u; __builtin_memcpy(&u, &h, 2);
    return u;
}

__device__ __forceinline__ short8 ldfrag(const bf16* p) { return *(const short8*)p; }
__device__ __forceinline__ short8 ldfrag(const float* p) {
    float4 a = *(const float4*)p;
    float4 b = *(const float4*)(p + 4);
    short8 r;
    r[0]=(short)bfbits(a.x); r[1]=(short)bfbits(a.y); r[2]=(short)bfbits(a.z); r[3]=(short)bfbits(a.w);
    r[4]=(short)bfbits(b.x); r[5]=(short)bfbits(b.y); r[6]=(short)bfbits(b.z); r[7]=(short)bfbits(b.w);
    return r;
}

// async global->LDS, 16B per lane. LDS dest must be wave-uniform base; HW adds lane*16.
__device__ __forceinline__ void stage16(const bf16* g, bf16* l) {
    __builtin_amdgcn_global_load_lds(
        (const __attribute__((address_space(1))) void*)g,
        (__attribute__((address_space(3))) void*)l, 16, 0, 0);
}

// fused f32 -> bf16 bulk convert over up to 3 segments, 8 elems/thread/iter
__global__ __launch_bounds__(256) void cvt3_kernel(const float* __restrict__ s0, bf16* __restrict__ d0, int n0,
                                                   const float* __restrict__ s1, bf16* __restrict__ d1, int n1,
                                                   const float* __restrict__ s2, bf16* __restrict__ d2, int n2)
{
    const int ntot = n0 + n1 + n2;
    int i = blockIdx.x * 256 + threadIdx.x;
    const int stride = gridDim.x * 256;
    for (; i < ntot; i += stride) {
        const float* s; bf16* d; int j = i;
        if (j < n0)              { s = s0; d = d0; }
        else if ((j -= n0) < n1) { s = s1; d = d1; }
        else                     { j -= n1; s = s2; d = d2; }
        const float4 a = ((const float4*)s)[2 * (size_t)j];
        const float4 b = ((const float4*)s)[2 * (size_t)j + 1];
        short8 r;
        r[0]=(short)bfbits(a.x); r[1]=(short)bfbits(a.y); r[2]=(short)bfbits(a.z); r[3]=(short)bfbits(a.w);
        r[4]=(short)bfbits(b.x); r[5]=(short)bfbits(b.y); r[6]=(short)bfbits(b.z); r[7]=(short)bfbits(b.w);
        ((short8*)d)[j] = r;
    }
}

// ---------- 256^2 deep-pipelined GEMM template (bf16 A,B) ----------
// A: Mx768 bf16. Bm: NOUTx768 bf16. Grid dim3(NOUT/256, 80), 512 thr.
// EPI=0: qkv scatter -> o0=Q, o1=K (B,H,N,D) bf16, o2=V^T (B,H,D,N) bf16.
// EPI=1: f32 store to o0 (ld=NOUT).
// Sync structure verified in R19/R20 (refcheck passed): 2 K-tile buffers,
// counted vmcnt(8) (tile kt drained, kt+1 in flight), lgkmcnt(0)+barrier
// before WAR overwrite, T2 both-sides swizzle, T5 setprio.
template<int NOUT, int EPI>
__global__ __launch_bounds__(512, 2) void gemm256(const bf16* __restrict__ A,
                                                  const bf16* __restrict__ Bm,
                                                  const float* __restrict__ bias,
                                                  void* __restrict__ o0,
                                                  void* __restrict__ o1,
                                                  void* __restrict__ o2)
{
    __shared__ alignas(16) bf16 As[2][256 * 64];   // 64KB
    __shared__ alignas(16) bf16 Bs[2][256 * 64];   // 64KB -> 128KB total, 1 blk/CU
    const int tid    = threadIdx.x;                // 0..511
    const int lane   = tid & 63;
    const int wv     = tid >> 6;                   // 0..7
    const int r16    = lane & 15;
    const int kg     = lane >> 4;                  // 0..3
    const int warp_m = wv >> 2;                    // 0..1
    const int warp_n = wv & 3;                     // 0..3

    constexpr int GX  = NOUT / 256;                // 9 (K1) / 3 (K3)
    constexpr int GY  = 20480 / 256;               // 80
    constexpr int NWG = GX * GY;                   // 720 / 240 (%8==0)
    int flat = blockIdx.y * GX + blockIdx.x;
    flat = (flat & 7) * (NWG / 8) + (flat >> 3);   // bijective XCD swizzle
    const int byy = flat / GX;
    const int bxx = flat - byy * GX;
    const int m0  = byy * 256;
    const int n0  = bxx * 256;

    // staging: thread t covers slot (row = j*64 + wv*8 + (lane>>3),
    // chunk = lane&7); slot holds GLOBAL chunk (lane&7)^(lane>>3) (row&7 ==
    // lane>>3) -> inverse T2 swizzle, linear LDS dest.
    const int srl  = wv * 8 + (lane >> 3);                  // 0..63
    const int gcol = ((lane & 7) ^ (lane >> 3)) * 8;        // elems
    const bf16* gA = A  + (size_t)(m0 + srl) * CDIM + gcol;
    const bf16* gB = Bm + (size_t)(n0 + srl) * CDIM + gcol;
    const int ldsb = wv * 512;                              // elems; + j*4096

    auto stageTile = [&](int kt, int buf) {
        const int k0 = kt * 64;
        #pragma unroll
        for (int j = 0; j < 4; j++)
            stage16(gA + (size_t)j * 64 * CDIM + k0, &As[buf][j * 4096 + ldsb]);
        #pragma unroll
        for (int j = 0; j < 4; j++)
            stage16(gB + (size_t)j * 64 * CDIM + k0, &Bs[buf][j * 4096 + ldsb]);
    };

    // read: fragment (row, ks, kg) -> chunk (ks*4+kg)^(row&7); row&7 == r16&7.
    const int arow = warp_m * 128 + r16;       // + m*16
    const int brow = warp_n * 64  + r16;       // + n*16
    const int csw0 = ((0 * 4 + kg) ^ (r16 & 7)) * 8;
    const int csw1 = ((1 * 4 + kg) ^ (r16 & 7)) * 8;

    f32x4 acc[8][4] = {};

    constexpr int NKT = CDIM / 64;   // 12
    stageTile(0, 0);                 // 8 issues
    stageTile(1, 1);                 // 8 issues (16 outstanding)
    for (int kt = 0; kt < NKT; ++kt) {
        const int buf = kt & 1;
        // tile kt = oldest 8 of <=16 outstanding; keep kt+1 in flight
        if (kt < NKT - 1) { asm volatile("s_waitcnt vmcnt(8)" ::: "memory"); }
        else              { asm volatile("s_waitcnt vmcnt(0)" ::: "memory"); }
        __builtin_amdgcn_s_barrier();
        asm volatile("" ::: "memory");
        #pragma unroll
        for (int ks = 0; ks < 2; ks++) {
            const int csw = ks ? csw1 : csw0;
            short8 af[8], bfm[4];
            #pragma unroll
            for (int m = 0; m < 8; m++)
                af[m] = *(const short8*)&As[buf][(arow + m * 16) * 64 + csw];
            #pragma unroll
            for (int n = 0; n < 4; n++)
                bfm[n] = *(const short8*)&Bs[buf][(brow + n * 16) * 64 + csw];
            __builtin_amdgcn_s_setprio(1);
            #pragma unroll
            for (int m = 0; m < 8; m++)
                #pragma unroll
                for (int n = 0; n < 4; n++)
                    acc[m][n] = MFMA16(af[m], bfm[n], acc[m][n]);
            __builtin_amdgcn_s_setprio(0);
        }
        // this wave's ds_reads are register-complete; pin with lgkmcnt(0),
        // then barrier => all waves done reading buf before overwrite.
        asm volatile("s_waitcnt lgkmcnt(0)" ::: "memory");
        __builtin_amdgcn_s_barrier();
        if (kt + 2 < NKT) stageTile(kt + 2, buf);   // WAR-safe overwrite
    }

    // Epilogue. C/D layout: col=r16 (in gn), row=kg*4+r (in gm).
    #pragma unroll
    for (int n = 0; n < 4; n++) {
        const int gn = n0 + warp_n * 64 + n * 16 + r16;
        const float bv = bias[gn];
        if constexpr (EPI == 0) {
            const int which = gn / CDIM;
            const int rem   = gn - which * CDIM;
            const int hh    = rem >> 6;
            const int dd    = rem & 63;
            #pragma unroll
            for (int m = 0; m < 8; m++) {
                const int gm0  = m0 + warp_m * 128 + m * 16 + kg * 4;  // 4-aligned
                const int bidx = gm0 / NTOK;                           // 320%4==0
                const int nn0  = gm0 - bidx * NTOK;
                float v[4];
                #pragma unroll
                for (int r = 0; r < 4; r++) v[r] = acc[m][n][r] + bv;
                if (which == 0) {
                    bf16* q = (bf16*)o0 + ((size_t)(bidx * NHEAD + hh) * NTOK + nn0) * 64 + dd;
                    #pragma unroll
                    for (int r = 0; r < 4; r++) q[(size_t)r * 64] = __float2bfloat16(v[r]);
                } else if (which == 1) {
                    bf16* k = (bf16*)o1 + ((size_t)(bidx * NHEAD + hh) * NTOK + nn0) * 64 + dd;
                    #pragma unroll
                    for (int r = 0; r < 4; r++) k[(size_t)r * 64] = __float2bfloat16(v[r]);
                } else {
                    ushort4 p;
                    unsigned short* ps = (unsigned short*)&p;
                    #pragma unroll
                    for (int r = 0; r < 4; r++) ps[r] = bfbits(v[r]);
                    *(ushort4*)((bf16*)o2 + ((size_t)(bidx * NHEAD + hh) * 64 + dd) * NTOK + nn0) = p;
                }
            }
        } else {
            float* out = (float*)o0;
            #pragma unroll
            for (int m = 0; m < 8; m++) {
                const int gm0 = m0 + warp_m * 128 + m * 16 + kg * 4;
                #pragma unroll
                for (int r = 0; r < 4; r++)
                    out[(size_t)(gm0 + r) * NOUT + gn] = acc[m][n][r] + bv;
            }
        }
    }
}

// ---------- simple 2-barrier 128^2 GEMM template (insurance paths only) ----------
template<int NOUT, int EPI, int BF16B>
__global__ __launch_bounds__(256) void gemm_bt16_s(const bf16* __restrict__ A,
                                                   const void* __restrict__ Bmv,
                                                   const float* __restrict__ bias,
                                                   void* __restrict__ o0,
                                                   void* __restrict__ o1,
                                                   void* __restrict__ o2)
{
    __shared__ alignas(16) bf16 As[128 * 32];
    __shared__ alignas(16) bf16 Bs[128 * 32];
    const int tid  = threadIdx.x;
    const int lane = tid & 63;
    const int wv   = tid >> 6;
    const int r16  = lane & 15;
    const int kg   = lane >> 4;

    constexpr int GX  = NOUT / 128;
    constexpr int NWG = GX * 160;
    int flat = blockIdx.y * GX + blockIdx.x;
    flat = (flat & 7) * (NWG >> 3) + (flat >> 3);
    const int byy = flat / GX;
    const int bxx = flat - byy * GX;
    const int m0  = byy * 128;
    const int n0  = bxx * 128;
    const int wm  = (wv & 1) * 64;
    const int wn  = (wv >> 1) * 64;

    const bf16*  Ab   = A + (size_t)m0 * CDIM;
    const float* Bb32 = (const float*)Bmv + (size_t)n0 * CDIM;

    const int ra0 = tid >> 2;
    const int ca0 = (tid & 3) * 8;

    bf16* lA0 = &As[(size_t)(wv * 64) * 8];
    bf16* lA1 = &As[(size_t)(wv * 64 + 256) * 8];

    f32x4 acc[4][4] = {};

    for (int k0 = 0; k0 < CDIM; k0 += 32) {
        short8 gb0 = ldfrag(Bb32 + (size_t)ra0        * CDIM + k0 + ca0);
        short8 gb1 = ldfrag(Bb32 + (size_t)(ra0 + 64) * CDIM + k0 + ca0);
        __syncthreads();
        stage16(Ab + (size_t)ra0        * CDIM + k0 + ca0, lA0);
        stage16(Ab + (size_t)(ra0 + 64) * CDIM + k0 + ca0, lA1);
        *(short8*)&Bs[(size_t)tid * 8]         = gb0;
        *(short8*)&Bs[(size_t)(tid + 256) * 8] = gb1;
        __syncthreads();

        short8 af[4], bfr[4];
        #pragma unroll
        for (int mt = 0; mt < 4; mt++)
            af[mt] = *(const short8*)&As[(wm + mt * 16 + r16) * 32 + kg * 8];
        #pragma unroll
        for (int nt = 0; nt < 4; nt++)
            bfr[nt] = *(const short8*)&Bs[(wn + nt * 16 + r16) * 32 + kg * 8];
        #pragma unroll
        for (int mt = 0; mt < 4; mt++)
            #pragma unroll
            for (int nt = 0; nt < 4; nt++)
                acc[mt][nt] = MFMA16(af[mt], bfr[nt], acc[mt][nt]);
    }

    #pragma unroll
    for (int nt = 0; nt < 4; nt++) {
        const int gn = n0 + wn + nt * 16 + r16;
        const float bv = bias[gn];
        if (EPI == 0) {
            const int which = gn / CDIM;
            const int rem   = gn - which * CDIM;
            const int hh    = rem >> 6;
            const int dd    = rem & 63;
            #pragma unroll
            for (int mt = 0; mt < 4; mt++) {
                const int gm0  = m0 + wm + mt * 16 + kg * 4;
                const int bidx = gm0 / NTOK;
                const int nn0  = gm0 - bidx * NTOK;
                float v[4];
                #pragma unroll
                for (int r = 0; r < 4; r++) v[r] = acc[mt][nt][r] + bv;
                if (which == 0) {
                    bf16* q = (bf16*)o0 + ((size_t)(bidx * NHEAD + hh) * NTOK + nn0) * 64 + dd;
                    #pragma unroll
                    for (int r = 0; r < 4; r++) q[(size_t)r * 64] = __float2bfloat16(v[r]);
                } else if (which == 1) {
                    bf16* k = (bf16*)o1 + ((size_t)(bidx * NHEAD + hh) * NTOK + nn0) * 64 + dd;
                    #pragma unroll
                    for (int r = 0; r < 4; r++) k[(size_t)r * 64] = __float2bfloat16(v[r]);
                } else {
                    ushort4 p;
                    unsigned short* ps = (unsigned short*)&p;
                    #pragma unroll
                    for (int r = 0; r < 4; r++) ps[r] = bfbits(v[r]);
                    *(ushort4*)((bf16*)o2 + ((size_t)(bidx * NHEAD + hh) * 64 + dd) * NTOK + nn0) = p;
                }
            }
        } else {
            float* out = (float*)o0;
            #pragma unroll
            for (int mt = 0; mt < 4; mt++) {
                const int gm0 = m0 + wm + mt * 16 + kg * 4;
                #pragma unroll
                for (int r = 0; r < 4; r++)
                    out[(size_t)(gm0 + r) * NOUT + gn] = acc[mt][nt][r] + bv;
            }
        }
    }
}

// ---------- attention: exact R12 kernel (best measured: 118-126us) ----------
#define ATTN_NWG (768 * 10)
__global__ __launch_bounds__(256, 4) void attn_kernel(const bf16* __restrict__ q_ws,
                                                      const bf16* __restrict__ k_ws,
                                                      const bf16* __restrict__ vt_ws,
                                                      bf16* __restrict__ attn,
                                                      const int* __restrict__ numt_p)
{
    __shared__ alignas(16) float S[32 * 320];
    int num_t = 64;
    if (numt_p) {
        int v = *numt_p;
        float f = __int_as_float(v);
        if (v >= 1 && v <= 319) num_t = v;
        else if (f >= 1.f && f <= 319.f) num_t = (int)f;
    }
    if (num_t <= 0 || num_t > NTOK || (num_t & 31)) num_t = 64;

    const int tid  = threadIdx.x;
    const int lane = tid & 63;
    const int w    = tid >> 6;
    const int r16  = lane & 15;
    const int kg   = lane >> 4;

    int blk = blockIdx.x;
    blk = (blk & 7) * (ATTN_NWG / 8) + (blk >> 3);
    const int bh  = blk / 10;
    const int qt  = blk - bh * 10;
    const int b   = bh / NHEAD;
    const int h   = bh - b * NHEAD;
    const int q0  = qt * 32;
    const int nk  = (q0 + 32 <= num_t) ? num_t : NTOK;
    const int nk16 = nk >> 4;

    const bf16* qp = q_ws  + (size_t)bh * NTOK * 64;
    const bf16* kp = k_ws  + (size_t)bh * NTOK * 64;
    const bf16* vp = vt_ws + (size_t)bh * 64 * NTOK;

    short8 qf[2][2];
    #pragma unroll
    for (int ks = 0; ks < 2; ks++)
        #pragma unroll
        for (int mt = 0; mt < 2; mt++)
            qf[ks][mt] = ldfrag(qp + (size_t)(q0 + mt * 16 + r16) * 64 + ks * 32 + kg * 8);

    const float scale = 0.125f;   // 1/sqrt(64)
    auto p1body = [&](int nt) {
        f32x4 a0 = {}, a1 = {};
        #pragma unroll
        for (int ks = 0; ks < 2; ks++) {
            short8 kf = ldfrag(kp + (size_t)(nt * 16 + r16) * 64 + ks * 32 + kg * 8);
            a0 = MFMA16(qf[ks][0], kf, a0);
            a1 = MFMA16(qf[ks][1], kf, a1);
        }
        const int col = nt * 16 + r16;
        #pragma unroll
        for (int r = 0; r < 4; r++) {
            const int ro  = kg * 4 + r;
            const int swz = (ro & 7) << 2;
            S[ro * 320        + (col ^ swz)] = a0[r] * scale;
            S[(16 + ro) * 320 + (col ^ swz)] = a1[r] * scale;
        }
    };
    if (nk16 == 20) {
        #pragma unroll
        for (int it = 0; it < 5; it++) p1body(w + it * 4);
    } else {
        for (int nt = w; nt < nk16; nt += 4) p1body(nt);
    }
    __syncthreads();

    {
        const int row = tid >> 3;
        const int sub = tid & 7;
        const int swzw = (row & 7) << 2;
        const int swzh = (row & 7) << 3;
        float* Sr = S + row * 320;
        bf16*  Pr = (bf16*)Sr;
        float mx = -1e30f;
        for (int c = sub * 4; c < nk; c += 32) {
            float4 t = *(float4*)&Sr[c ^ swzw];
            mx = fmaxf(mx, fmaxf(fmaxf(t.x, t.y), fmaxf(t.z, t.w)));
        }
        #pragma unroll
        for (int m = 1; m < 8; m <<= 1) mx = fmaxf(mx, __shfl_xor(mx, m));
        float sum = 0.f;
        for (int c = sub * 4; c < nk; c += 32) {
            float4 t = *(float4*)&Sr[c ^ swzw];
            t.x = __expf(t.x - mx); t.y = __expf(t.y - mx);
            t.z = __expf(t.z - mx); t.w = __expf(t.w - mx);
            sum += t.x + t.y + t.z + t.w;
            ushort4 p;
            p.x = bfbits(t.x); p.y = bfbits(t.y); p.z = bfbits(t.z); p.w = bfbits(t.w);
            *(ushort4*)&Pr[c ^ swzh] = p;
        }
        #pragma unroll
        for (int m = 1; m < 8; m <<= 1) sum += __shfl_xor(sum, m);
        if (sub == 0) Sr[316 ^ swzw] = 1.0f / sum;
    }
    __syncthreads();

    const int mt  = w & 1;
    const int ntb = w >> 1;
    const int prow = mt * 16 + r16;
    const bf16* Pbr = (const bf16*)(S + prow * 320);
    const int pswzh = (prow & 7) << 3;
    f32x4 o[2] = {};
    auto p3body = [&](int ks) {
        short8 af = *(const short8*)&Pbr[(ks * 32 + kg * 8) ^ pswzh];
        #pragma unroll
        for (int i = 0; i < 2; i++) {
            const int nt = ntb + i * 2;
            short8 vf = ldfrag(vp + (size_t)(nt * 16 + r16) * NTOK + ks * 32 + kg * 8);
            o[i] = MFMA16(af, vf, o[i]);
        }
    };
    if (nk == NTOK) {
        #pragma unroll
        for (int ks = 0; ks < 10; ks++) p3body(ks);
    } else {
        for (int ks = 0; ks < (nk >> 5); ks++) p3body(ks);
    }
    #pragma unroll
    for (int i = 0; i < 2; i++) {
        const int nt = ntb + i * 2;
        const int dd = nt * 16 + r16;
        #pragma unroll
        for (int r = 0; r < 4; r++) {
            const int qrow  = mt * 16 + kg * 4 + r;
            const float invs = S[qrow * 320 + (316 ^ ((qrow & 7) << 2))];
            const float val = o[i][r] * invs;
            const int token = q0 + qrow;
            attn[(((size_t)b * NTOK + token) * NHEAD + h) * 64 + dd] = __float2bfloat16(val);
        }
    }
}

extern "C" void kernel_launch(void* const* d_in, const int* in_sizes, int n_in,
                              void* d_out, int out_size, void* d_ws, size_t ws_size,
                              hipStream_t stream)
{
    float* out = (float*)d_out;

    const float *x = nullptr, *w_qkv = nullptr, *b_qkv = nullptr,
                *w_proj = nullptr, *b_proj = nullptr;
    const int* numt_p = nullptr;
    for (int i = 0; i < n_in; i++) {
        switch (in_sizes[i]) {
            case 15728640: x      = (const float*)d_in[i]; break;  // (64,320,768)
            case 1769472:  w_qkv  = (const float*)d_in[i]; break;  // (2304,768)
            case 2304:     b_qkv  = (const float*)d_in[i]; break;  // (2304,)
            case 589824:   w_proj = (const float*)d_in[i]; break;  // (768,768)
            case 768:      b_proj = (const float*)d_in[i]; break;  // (768,)
            case 1:        if (!numt_p) numt_p = (const int*)d_in[i]; break;
            default: break;
        }
    }
    if (!x || !w_qkv || !b_qkv || !w_proj || !b_proj) return;

    const size_t per      = (size_t)64 * NHEAD * NTOK * 64;  // 15,728,640 elems
    const size_t wq_elems = (size_t)2304 * 768;              // 1,769,472
    const size_t wp_elems = (size_t)768 * 768;               //   589,824
    const size_t base_need = 4 * per * sizeof(bf16);               // 125,829,120
    const size_t full_need = base_need + (wq_elems + wp_elems) * sizeof(bf16); // +4.7MB
    if (ws_size < base_need) return;
    const bool full = ws_size >= full_need;

    bf16* q_ws  = (bf16*)d_ws;
    bf16* k_ws  = q_ws  + per;
    bf16* vt_ws = k_ws  + per;
    bf16* attn  = vt_ws + per;   // doubles as x_bf16 (dead once K2 writes attn)
    bf16* x16   = attn;          // exact fit: per elems
    bf16* wq16  = attn + per;    // only touched when `full`
    bf16* wp16  = wq16 + wq_elems;

    // K0: fused f32->bf16 conversions (one launch)
    if (full)
        cvt3_kernel<<<2048, 256, 0, stream>>>(x, x16, (int)(per / 8),
                                              w_qkv, wq16, (int)(wq_elems / 8),
                                              w_proj, wp16, (int)(wp_elems / 8));
    else
        cvt3_kernel<<<2048, 256, 0, stream>>>(x, x16, (int)(per / 8),
                                              x, x16, 0, x, x16, 0);

    // K1: qkv = x @ w_qkv^T + b_qkv, scattered to Q,K,(V^T)  [256^2 pipeline]
    if (full)
        gemm256<2304, 0><<<dim3(9, 80), 512, 0, stream>>>(
            x16, wq16, b_qkv, q_ws, k_ws, vt_ws);
    else
        gemm_bt16_s<2304, 0, 0><<<dim3(18, 160), 256, 0, stream>>>(
            x16, w_qkv, b_qkv, q_ws, k_ws, vt_ws);

    // K2: attention  [R12 exact]
    attn_kernel<<<ATTN_NWG, 256, 0, stream>>>(q_ws, k_ws, vt_ws, attn, numt_p);

    // K3: out = attn @ w_proj^T + b_proj (f32 stores)  [256^2 pipeline]
    if (full)
        gemm256<768, 1><<<dim3(3, 80), 512, 0, stream>>>(
            attn, wp16, b_proj, out, nullptr, nullptr);
    else
        gemm_bt16_s<768, 1, 0><<<dim3(6, 160), 256, 0, stream>>>(
            attn, w_proj, b_proj, out, nullptr, nullptr);
}